// Round 2
// baseline (396.424 us; speedup 1.0000x reference)
//
#include <hip/hip_runtime.h>
#include <hip/hip_bf16.h>

#define NN 50000
#define NE 800000
#define IND 128
#define NH 8
#define EBLK 256          // binning blocks
#define EPB 3125          // NE / EBLK
#define NBUK 391          // buckets of 128 dst nodes
#define NBUKP 392         // padded (bucket 391 empty -> offset == NE)
#define GH (NBUKP * EBLK) // 100352
#define PREPB 308         // prep blocks: 78848 / 256

typedef __hip_bfloat16 bf16;
typedef __attribute__((ext_vector_type(8))) short short8;
typedef __attribute__((ext_vector_type(8))) __bf16 bf16x8;
typedef __attribute__((ext_vector_type(4))) float floatx4;
typedef __attribute__((ext_vector_type(2))) float floatx2;

static __device__ __forceinline__ short f2bf_bits(float f) {
    unsigned u = __float_as_uint(f);
    u = (u + 0x7fffu + ((u >> 16) & 1u)) >> 16;
    return (short)u;
}
static __device__ __forceinline__ float bf2f(bf16 v) { return __bfloat162float(v); }
static __device__ __forceinline__ floatx2 up2(unsigned av) {
    floatx2 r;
    r.x = __uint_as_float(av << 16);
    r.y = __uint_as_float(av & 0xffff0000u);
    return r;
}
static __device__ __forceinline__ unsigned pk2(float a, float b) {
    return (unsigned)(unsigned short)f2bf_bits(a) | ((unsigned)(unsigned short)f2bf_bits(b) << 16);
}

// exclusive scan of bsum[0..NBUKP) into gb[0..512); mirrors scang1's proven pattern
static __device__ __forceinline__ void scan_buckets(const int* __restrict__ bsum,
        int* sp, int* gb, int tid) {
    int v0 = (2 * tid < NBUKP) ? bsum[2 * tid] : 0;
    int v1 = (2 * tid + 1 < NBUKP) ? bsum[2 * tid + 1] : 0;
    int c = v0 + v1;
    sp[tid] = c; __syncthreads();
    int val = c;
#pragma unroll
    for (int off = 1; off < 256; off <<= 1) {
        int t = (tid >= off) ? sp[tid - off] : 0;
        __syncthreads();
        val += t; sp[tid] = val;
        __syncthreads();
    }
    int pex = val - c;
    gb[2 * tid] = pex;
    gb[2 * tid + 1] = pex + v0;
    __syncthreads();
}

// ---------------- merged: edge bin counting (blocks 0..255) + weight prep (blocks 256..563) ----
__global__ __launch_bounds__(256) void bin_count_prep_kernel(const int* __restrict__ edst,
        int* __restrict__ ghist,
        const float* __restrict__ gcn1_w, const float* __restrict__ gcn2_w,
        const float* __restrict__ gat1_w, const float* __restrict__ gat2_w,
        const float* __restrict__ as1, const float* __restrict__ ad1,
        const float* __restrict__ as2, const float* __restrict__ ad2,
        bf16* __restrict__ wT1, bf16* __restrict__ wT2,
        bf16* __restrict__ wgT1, bf16* __restrict__ wgT2,
        float* __restrict__ was1, float* __restrict__ wad1,
        float* __restrict__ was2, float* __restrict__ wad2) {
    __shared__ int hsh[NBUKP];
    const int tid = threadIdx.x;
    if (blockIdx.x < EBLK) {
        const int blk = blockIdx.x;
        for (int b = tid; b < NBUKP; b += 256) hsh[b] = 0;
        __syncthreads();
        const int e0 = blk * EPB;
        for (int e = e0 + tid; e < e0 + EPB; e += 256)
            atomicAdd(&hsh[edst[e] >> 7], 1);
        __syncthreads();
        for (int b = tid; b < NBUKP; b += 256)
            ghist[b * EBLK + blk] = hsh[b];
    } else {
        int idx = (blockIdx.x - EBLK) * 256 + tid;
        if (idx < 8192) {
            int m = idx >> 7, k = idx & 127;
            ((short*)wT1)[idx] = f2bf_bits(gcn1_w[(long)k * 64 + m]);
        } else if (idx < 12288) {
            int i = idx - 8192;
            int m = i >> 6, k = i & 63;
            ((short*)wT2)[i] = f2bf_bits(gcn2_w[(long)k * 64 + m]);
        } else if (idx < 45056) {
            int i = idx - 12288;
            int m = i >> 9, k = i & 511;
            int h = k >> 6, c = k & 63;
            ((short*)wgT1)[i] = f2bf_bits(gat1_w[(long)c * 512 + h * 64 + m]);
        } else if (idx < 77824) {
            int i = idx - 45056;
            int m = i >> 9, k = i & 511;
            int h = k >> 6, c = k & 63;
            ((short*)wgT2)[i] = (m < 32) ? f2bf_bits(gat2_w[(long)c * 256 + h * 32 + m]) : (short)0;
        } else if (idx < 78336) {
            int i = idx - 77824;
            int h = i >> 6, c = i & 63;
            const float* wrow = gat1_w + (long)c * 512 + h * 64;
            float s = 0.f, d = 0.f;
            for (int cc = 0; cc < 64; ++cc) {
                float w = wrow[cc];
                s += w * as1[h * 64 + cc];
                d += w * ad1[h * 64 + cc];
            }
            was1[i] = s; wad1[i] = d;
        } else if (idx < 78848) {
            int i = idx - 78336;
            int h = i >> 6, c = i & 63;
            const float* wrow = gat2_w + (long)c * 256 + h * 32;
            float s = 0.f, d = 0.f;
            for (int cc = 0; cc < 32; ++cc) {
                float w = wrow[cc];
                s += w * as2[h * 32 + cc];
                d += w * ad2[h * 32 + cc];
            }
            was2[i] = s; wad2[i] = d;
        }
    }
}

__global__ __launch_bounds__(256) void scang1_kernel(const int* __restrict__ src,
        int* __restrict__ pre, int* __restrict__ bsum, int n) {
    __shared__ int sh[256];
    const int tid = threadIdx.x;
    const int idx = blockIdx.x * 256 + tid;
    int c = (idx < n) ? src[idx] : 0;
    sh[tid] = c; __syncthreads();
    int val = c;
#pragma unroll
    for (int off = 1; off < 256; off <<= 1) {
        int t = (tid >= off) ? sh[tid - off] : 0;
        __syncthreads();
        val += t; sh[tid] = val;
        __syncthreads();
    }
    if (idx < n) pre[idx] = val - c;
    if (tid == 255) bsum[blockIdx.x] = val;
}

// bin_scatter inlines the bucket-level scan (scang2 kernel removed)
__global__ __launch_bounds__(256) void bin_scatter_kernel(const int* __restrict__ esrc,
        const int* __restrict__ edst, const int* __restrict__ gpre,
        const int* __restrict__ bsum, unsigned* __restrict__ ebuf) {
    __shared__ int cur[NBUKP];
    __shared__ int sp[256], gb[512];
    const int tid = threadIdx.x, blk = blockIdx.x;
    scan_buckets(bsum, sp, gb, tid);
    for (int b = tid; b < NBUKP; b += 256)
        cur[b] = gpre[b * EBLK + blk] + gb[b];
    __syncthreads();
    const int e0 = blk * EPB;
    for (int e = e0 + tid; e < e0 + EPB; e += 256) {
        int d = edst[e], s = esrc[e];
        int pos = atomicAdd(&cur[d >> 7], 1);
        ebuf[pos] = ((unsigned)(d & 127) << 16) | (unsigned)s;
    }
}

__global__ __launch_bounds__(256) void bucket_finalize_kernel(const unsigned* __restrict__ ebuf,
        const int* __restrict__ gpre, const int* __restrict__ bsum,
        int* __restrict__ rowptr, float* __restrict__ dinv, int* __restrict__ csrc) {
    __shared__ int lh[128], lcur[128], sc[256];
    __shared__ int sp[256], gb[512];
    const int bu = blockIdx.x, tid = threadIdx.x;
    scan_buckets(bsum, sp, gb, tid);
    const int seg_beg = gpre[bu * EBLK] + gb[bu];
    const int seg_end = gpre[(bu + 1) * EBLK] + gb[bu + 1];
    if (tid < 128) lh[tid] = 0;
    __syncthreads();
    for (int i = seg_beg + tid; i < seg_end; i += 256)
        atomicAdd(&lh[ebuf[i] >> 16], 1);
    __syncthreads();
    int c = (tid < 128) ? lh[tid] : 0;
    sc[tid] = c; __syncthreads();
    int val = c;
#pragma unroll
    for (int off = 1; off < 256; off <<= 1) {
        int t = (tid >= off) ? sc[tid - off] : 0;
        __syncthreads();
        val += t; sc[tid] = val;
        __syncthreads();
    }
    int excl = val - c;
    if (tid < 128) {
        lcur[tid] = excl;
        int node = bu * 128 + tid;
        if (node < NN) {
            rowptr[node] = seg_beg + excl;
            dinv[node] = rsqrtf((float)c + 1.f);
        }
    }
    if (bu == 0 && tid == 0) rowptr[NN] = NE;
    __syncthreads();
    for (int i = seg_beg + tid; i < seg_end; i += 256) {
        unsigned u = ebuf[i];
        int pos = atomicAdd(&lcur[u >> 16], 1);
        csrc[seg_beg + pos] = (int)(u & 0xffffu);
    }
}

// ---------------- MFMA matmul v2: NO LDS ----------------
template<int K, int EPI, bool AF32>
__global__ __launch_bounds__(256) void mm2_kernel(const void* __restrict__ A,
        const bf16* __restrict__ wT, void* __restrict__ C,
        const float* __restrict__ bias, const float* __restrict__ rowscale,
        int nrows, int M) {
    const int row0 = blockIdx.x * 64;
    const int tid = threadIdx.x;
    const int lane = tid & 63, wave = tid >> 6;
    const int lr = lane & 15, q = lane >> 4;
    const int row = row0 + wave * 16 + lr;
    const bool rok = row < nrows;
    constexpr int NC = (EPI == 4) ? 2 : 4;
    floatx4 acc[NC] = {};
#pragma unroll 4
    for (int k0 = 0; k0 < K; k0 += 32) {
        short8 av = {0, 0, 0, 0, 0, 0, 0, 0};
        if (rok) {
            if (AF32) {
                const float* apf = (const float*)A + (long)row * K + q * 8 + k0;
                floatx4 va = *(const floatx4*)apf;
                floatx4 vb = *(const floatx4*)(apf + 4);
#pragma unroll
                for (int j = 0; j < 4; ++j) { av[j] = f2bf_bits(va[j]); av[4 + j] = f2bf_bits(vb[j]); }
            } else {
                av = *(const short8*)((const short*)A + (long)row * K + q * 8 + k0);
            }
        }
        bf16x8 a = __builtin_bit_cast(bf16x8, av);
#pragma unroll
        for (int c = 0; c < NC; ++c) {
            bf16x8 b = __builtin_bit_cast(bf16x8,
                *(const short8*)((const short*)wT + (long)(c * 16 + lr) * K + k0 + q * 8));
            acc[c] = __builtin_amdgcn_mfma_f32_16x16x32_bf16(a, b, acc[c], 0, 0, 0);
        }
    }
    if (EPI == 4) {
#pragma unroll
        for (int r = 0; r < 4; ++r) {
            int orow = row0 + wave * 16 + q * 4 + r;
            float v0 = acc[0][r] * 0.125f + bias[lr];
            float v1 = acc[1][r] * 0.125f + bias[16 + lr];
            float m = fmaxf(v0, v1);
#pragma unroll
            for (int off = 1; off < 16; off <<= 1) m = fmaxf(m, __shfl_xor(m, off));
            float s = __expf(v0 - m) + __expf(v1 - m);
#pragma unroll
            for (int off = 1; off < 16; off <<= 1) s += __shfl_xor(s, off);
            float ls = m + logf(s);
            if (orow < nrows) {
                ((float*)C)[(long)orow * 32 + lr] = v0 - ls;
                ((float*)C)[(long)orow * 32 + 16 + lr] = v1 - ls;
            }
        }
        return;
    }
#pragma unroll
    for (int c = 0; c < NC; ++c)
#pragma unroll
        for (int r = 0; r < 4; ++r) {
            int orow = row0 + wave * 16 + q * 4 + r;
            int col = c * 16 + lr;
            if (orow < nrows && col < M) {
                long o = (long)orow * M + col;
                float v = acc[c][r];
                if (EPI == 0) ((float*)C)[o] = v;
                else if (EPI == 2) {
                    v = v * 0.125f + bias[col];
                    ((bf16*)C)[o] = __float2bfloat16(fmaxf(v, 0.f));
                } else {
                    ((bf16*)C)[o] = __float2bfloat16(rowscale[orow] * v);
                }
            }
        }
}

// ---------------- fused GCN aggregate + bias + BN + ReLU ----------------
__global__ __launch_bounds__(256) void gcn_fused_kernel(const int* __restrict__ rowptr,
        const int* __restrict__ csrc, const float* __restrict__ dinv,
        const bf16* __restrict__ hin, const float* __restrict__ b,
        const float* __restrict__ gamma, const float* __restrict__ beta,
        const float* __restrict__ mean, const float* __restrict__ var,
        bf16* __restrict__ actout) {
    const int node = blockIdx.x * 4 + (threadIdx.x >> 6);
    if (node >= NN) return;
    const int lane = threadIdx.x & 63;
    const int eslot = lane >> 5, cp = lane & 31;
    const unsigned cpo = 4u * (unsigned)cp;
    const int beg = rowptr[node], end = rowptr[node + 1];
    const float di = dinv[node];
    floatx2 acc2 = {0.f, 0.f};
    const int kup = ((end - beg) + 7) & ~7;
    for (int k0 = 0; k0 < kup; k0 += 8) {
        int s_[4]; float w_[4];
#pragma unroll
        for (int u = 0; u < 4; ++u) {
            int ei = beg + k0 + 2 * u + eslot;
            int ok = ei < end;
            s_[u] = csrc[ok ? ei : beg];
            w_[u] = ok ? 1.f : 0.f;
        }
        unsigned av_[4];
#pragma unroll
        for (int u = 0; u < 4; ++u)
            av_[u] = *(const unsigned*)((const char*)hin + ((unsigned)s_[u] * 128u + cpo));
#pragma unroll
        for (int u = 0; u < 4; ++u) {
            floatx2 a2 = up2(av_[u]);
            acc2 += a2 * w_[u];
        }
    }
    acc2.x += __shfl_xor(acc2.x, 32);
    acc2.y += __shfl_xor(acc2.y, 32);
    {
        unsigned sv = *(const unsigned*)((const char*)hin + ((unsigned)node * 128u + cpo));
        acc2 += up2(sv);
    }
    int c0 = 2 * cp, c1 = c0 + 1;
    float x0 = acc2.x * di + b[c0];
    float x1 = acc2.y * di + b[c1];
    x0 = (x0 - mean[c0]) * rsqrtf(var[c0] + 1e-5f) * gamma[c0] + beta[c0];
    x1 = (x1 - mean[c1]) * rsqrtf(var[c1] + 1e-5f) * gamma[c1] + beta[c1];
    if (eslot == 0)
        *(unsigned*)((unsigned short*)actout + (long)node * 64 + c0) =
            pk2(fmaxf(x0, 0.f), fmaxf(x1, 0.f));
}

// es[n,h] = <act[n,:], was[h,:]>
__global__ __launch_bounds__(256) void scores_kernel(const bf16* __restrict__ actb,
        const float* __restrict__ was, const float* __restrict__ wad,
        float* __restrict__ es, float* __restrict__ ed, int n) {
    const int node = blockIdx.x * 4 + (threadIdx.x >> 6);
    if (node >= n) return;
    const int lane = threadIdx.x & 63;
    const int h = lane >> 3, cg = lane & 7;
    short8 a8 = *(const short8*)((const short*)actb + (long)node * 64 + cg * 8);
    const float* wsp = was + h * 64 + cg * 8;
    const float* wdp = wad + h * 64 + cg * 8;
    floatx4 ws0 = *(const floatx4*)wsp, ws1 = *(const floatx4*)(wsp + 4);
    floatx4 wd0 = *(const floatx4*)wdp, wd1 = *(const floatx4*)(wdp + 4);
    float s = 0.f, d = 0.f;
#pragma unroll
    for (int j = 0; j < 4; ++j) {
        float v0 = bf2f(__builtin_bit_cast(bf16, a8[j]));
        float v1 = bf2f(__builtin_bit_cast(bf16, a8[4 + j]));
        s += v0 * ws0[j] + v1 * ws1[j];
        d += v0 * wd0[j] + v1 * wd1[j];
    }
#pragma unroll
    for (int off = 1; off < 8; off <<= 1) {
        s += __shfl_xor(s, off);
        d += __shfl_xor(d, off);
    }
    if (cg == 0) { es[node * NH + h] = s; ed[node * NH + h] = d; }
}

// ---------------- GAT aggregation (self-shifted softmax), issue-minimized ----------------
// Phase A: ONE coalesced csrc load + shfl distribution; uniform-branch skip of dead
//          edge-blocks (deg is wave-uniform -> s_cbranch, no divergence).
// Phase B: edge-pair layout (ep=lane>>5 edge parity, cp=lane&31 channel-pair); each
//          source row is loaded once per edge (not twice), each lane keeps all 8 head
//          accumulators as floatx2 (packable FMAs). Cross-parity shfl reduce at end.
__global__ __launch_bounds__(256) void gat_agg_kernel(const int* __restrict__ rowptr,
        const int* __restrict__ csrc, const float* __restrict__ es, const float* __restrict__ ed,
        const bf16* __restrict__ actb, bf16* __restrict__ agg) {
    __shared__ __align__(16) float salpha[4][512];
    __shared__ int ssrcs[4][64];
    __shared__ __align__(16) float sself[4][8];
    const int wv = threadIdx.x >> 6;
    const int node = blockIdx.x * 4 + wv;
    if (node >= NN) return;
    const int lane = threadIdx.x & 63;
    const int h = lane & 7, slot = lane >> 3;
    const int beg = rowptr[node], end = rowptr[node + 1];
    const int deg = end - beg;
    const float edr = *(const float*)((const char*)ed + ((unsigned)node * 32u + (unsigned)h * 4u));

    float selfe = *(const float*)((const char*)es + ((unsigned)node * 32u + (unsigned)h * 4u)) + edr;
    selfe = selfe > 0.f ? selfe : 0.2f * selfe;

    if (deg <= 64) {
        // ---- Phase A ----
        const int nb = (deg + 7) >> 3;          // live 8-edge blocks (wave-uniform)
        const int dm1 = (deg > 0) ? deg - 1 : 0;
        int s_all = csrc[beg + (lane < deg ? lane : dm1)];   // one coalesced load
        ssrcs[wv][lane] = s_all;                             // one ds_write stages all srcs
        float ex_r[8];
        float den = 0.f;
#pragma unroll
        for (int b = 0; b < 8; ++b) {
            ex_r[b] = 0.f;
            if (b < nb) {                        // wave-uniform branch
                int k = b * 8 + slot;
                int s = __shfl(s_all, k);        // src id from the cooperative load
                float e = *(const float*)((const char*)es + ((unsigned)s * 32u + (unsigned)h * 4u)) + edr;
                e = e > 0.f ? e : 0.2f * e;
                float ex = __expf(e - selfe);
                ex_r[b] = (k < deg) ? ex : 0.f;
                den += ex_r[b];
            }
        }
        den += __shfl_xor(den, 8);
        den += __shfl_xor(den, 16);
        den += __shfl_xor(den, 32);
        const float invden = 1.f / (den + 1.f);

        // stage alphas (alpha(k,h) at salpha[k*8+h]) + self
#pragma unroll
        for (int b = 0; b < 8; ++b)
            if (b < nb) salpha[wv][b * 64 + lane] = ex_r[b] * invden;
        if (slot == 0) sself[wv][h] = invden;

        // ---- Phase B: edge-pair gather ----
        const int ep = lane >> 5, cp = lane & 31;
        const unsigned cpo = 4u * (unsigned)cp;
        floatx2 acc2[8] = {};
        const int kup4 = (deg + 3) & ~3;         // alpha zero-filled within live blocks
        for (int k0 = 0; k0 < kup4; k0 += 4) {
            int kA = k0 + ep, kB = k0 + 2 + ep;
            int sA = ssrcs[wv][kA];
            int sB = ssrcs[wv][kB];
            unsigned avA = *(const unsigned*)((const char*)actb + ((unsigned)sA * 128u + cpo));
            unsigned avB = *(const unsigned*)((const char*)actb + ((unsigned)sB * 128u + cpo));
            floatx4 alA0 = *(const floatx4*)&salpha[wv][kA * 8];
            floatx4 alA1 = *(const floatx4*)&salpha[wv][kA * 8 + 4];
            floatx4 alB0 = *(const floatx4*)&salpha[wv][kB * 8];
            floatx4 alB1 = *(const floatx4*)&salpha[wv][kB * 8 + 4];
            floatx2 aA = up2(avA), aB = up2(avB);
            acc2[0] += aA * alA0[0]; acc2[1] += aA * alA0[1];
            acc2[2] += aA * alA0[2]; acc2[3] += aA * alA0[3];
            acc2[4] += aA * alA1[0]; acc2[5] += aA * alA1[1];
            acc2[6] += aA * alA1[2]; acc2[7] += aA * alA1[3];
            acc2[0] += aB * alB0[0]; acc2[1] += aB * alB0[1];
            acc2[2] += aB * alB0[2]; acc2[3] += aB * alB0[3];
            acc2[4] += aB * alB1[0]; acc2[5] += aB * alB1[1];
            acc2[6] += aB * alB1[2]; acc2[7] += aB * alB1[3];
        }
        // cross-parity reduce: both halves end with the full edge sum
#pragma unroll
        for (int hh = 0; hh < 8; ++hh) {
            acc2[hh].x += __shfl_xor(acc2[hh].x, 32);
            acc2[hh].y += __shfl_xor(acc2[hh].y, 32);
        }
        {   // self edge
            unsigned sv = *(const unsigned*)((const char*)actb + ((unsigned)node * 128u + cpo));
            floatx2 a2 = up2(sv);
            floatx4 s0 = *(const floatx4*)&sself[wv][0];
            floatx4 s1 = *(const floatx4*)&sself[wv][4];
            acc2[0] += a2 * s0[0]; acc2[1] += a2 * s0[1];
            acc2[2] += a2 * s0[2]; acc2[3] += a2 * s0[3];
            acc2[4] += a2 * s1[0]; acc2[5] += a2 * s1[1];
            acc2[6] += a2 * s1[2]; acc2[7] += a2 * s1[3];
        }
        // each parity half stores 4 heads
        const int h0 = ep * 4;
#pragma unroll
        for (int j = 0; j < 4; ++j) {
            int hh = h0 + j;
            *(unsigned*)((char*)agg + ((unsigned)node * 1024u + (unsigned)hh * 128u + cpo)) =
                pk2(acc2[hh].x, acc2[hh].y);
        }
    } else {
        // ---- fallback (deg>64, rare): streaming two-pass, full-wave per edge ----
        float acc[NH] = {0.f, 0.f, 0.f, 0.f, 0.f, 0.f, 0.f, 0.f};
        float den = 0.f;
        for (int base = beg; base < end; base += 8) {
            int ei = base + slot;
            if (ei < end) {
                int s = csrc[ei];
                float e = es[s * NH + h] + edr;
                e = e > 0.f ? e : 0.2f * e;
                den += __expf(e - selfe);
            }
        }
        den += __shfl_xor(den, 8);
        den += __shfl_xor(den, 16);
        den += __shfl_xor(den, 32);
        const float invden = 1.f / (den + 1.f);
        for (int base = beg; base < end; base += 8) {
            int ei = base + slot;
            float al = 0.f; int sl = 0;
            if (ei < end) {
                sl = csrc[ei];
                float e = es[sl * NH + h] + edr;
                e = e > 0.f ? e : 0.2f * e;
                al = __expf(e - selfe) * invden;
            }
            salpha[wv][lane] = al;
            if (h == 0) ssrcs[wv][slot] = sl;
            int ecnt = end - base; if (ecnt > 8) ecnt = 8;
            for (int j = 0; j < ecnt; ++j) {
                int s = ssrcs[wv][j];
                float a = bf2f(actb[(long)s * 64 + lane]);
                floatx4 al0 = *(const floatx4*)&salpha[wv][j * 8];
                floatx4 al1 = *(const floatx4*)&salpha[wv][j * 8 + 4];
                acc[0] += al0[0] * a; acc[1] += al0[1] * a;
                acc[2] += al0[2] * a; acc[3] += al0[3] * a;
                acc[4] += al1[0] * a; acc[5] += al1[1] * a;
                acc[6] += al1[2] * a; acc[7] += al1[3] * a;
            }
        }
        {
            if (slot == 0) sself[wv][h] = invden;
            float a = bf2f(actb[(long)node * 64 + lane]);
            floatx4 s0 = *(const floatx4*)&sself[wv][0];
            floatx4 s1 = *(const floatx4*)&sself[wv][4];
            acc[0] += s0[0] * a; acc[1] += s0[1] * a;
            acc[2] += s0[2] * a; acc[3] += s0[3] * a;
            acc[4] += s1[0] * a; acc[5] += s1[1] * a;
            acc[6] += s1[2] * a; acc[7] += s1[3] * a;
        }
#pragma unroll
        for (int hh = 0; hh < NH; ++hh)
            agg[(long)node * 512 + hh * 64 + lane] = __float2bfloat16(acc[hh]);
    }
}

// ---------------- launch ----------------
extern "C" void kernel_launch(void* const* d_in, const int* in_sizes, int n_in,
                              void* d_out, int out_size, void* d_ws, size_t ws_size,
                              hipStream_t stream) {
    const float* x        = (const float*)d_in[0];
    const int*   eidx     = (const int*)d_in[1];
    const float* gcn1_w   = (const float*)d_in[2];
    const float* gcn1_b   = (const float*)d_in[3];
    const float* bn1_g    = (const float*)d_in[4];
    const float* bn1_b    = (const float*)d_in[5];
    const float* bn1_m    = (const float*)d_in[6];
    const float* bn1_v    = (const float*)d_in[7];
    const float* gat1_w   = (const float*)d_in[8];
    const float* gat1_as  = (const float*)d_in[9];
    const float* gat1_ad  = (const float*)d_in[10];
    const float* gat1_b   = (const float*)d_in[11];
    const float* gcn2_w   = (const float*)d_in[12];
    const float* gcn2_b   = (const float*)d_in[13];
    const float* bn2_g    = (const float*)d_in[14];
    const float* bn2_b    = (const float*)d_in[15];
    const float* bn2_m    = (const float*)d_in[16];
    const float* bn2_v    = (const float*)d_in[17];
    const float* gat2_w   = (const float*)d_in[18];
    const float* gat2_as  = (const float*)d_in[19];
    const float* gat2_ad  = (const float*)d_in[20];
    const float* gat2_b   = (const float*)d_in[21];
    float* out = (float*)d_out;

    const int* esrc = eidx;
    const int* edst = eidx + NE;

    // workspace (~78 MB, < proven-safe 110.6 MB)
    float* ws = (float*)d_ws;
    int*      ghist  = (int*)ws;                        // GH
    int*      gpre   = ghist + GH;                      // GH
    int*      gbsum  = gpre + GH;                       // 512 (unscanned block sums)
    unsigned* ebuf   = (unsigned*)(gbsum + 512);        // NE
    int*      rowptr = (int*)(ebuf + NE);               // 50048
    int*      csrc   = rowptr + 50048;                  // NE
    float*    dinv   = (float*)(csrc + NE);             // 50048
    float*    es     = dinv + 50048;                    // 400000
    float*    ed     = es + 400000;                     // 400000
    float*    was1   = ed + 400000;                     // 512
    float*    wad1   = was1 + 512;                      // 512
    float*    was2   = wad1 + 512;                      // 512
    float*    wad2   = was2 + 512;                      // 512
    bf16*     wT1    = (bf16*)(wad2 + 512);             // 64*128
    bf16*     wT2    = wT1 + 64 * 128;                  // 64*64
    bf16*     wgT1   = wT2 + 64 * 64;                   // 64*512
    bf16*     wgT2   = wgT1 + 64 * 512;                 // 64*512
    bf16*     actb   = wgT2 + 64 * 512;                 // N*64 bf16
    bf16*     mmbf   = actb + (size_t)NN * 64;          // N*64 bf16
    bf16*     agg    = mmbf + (size_t)NN * 64;          // N*512 bf16

    auto cdiv = [](long a, long b) { return (int)((a + b - 1) / b); };
    const int GB = cdiv(NN, 64);
    const int NB = cdiv(NN, 4);

    // ---- CSR build ----
    bin_count_prep_kernel<<<EBLK + PREPB, 256, 0, stream>>>(edst, ghist,
        gcn1_w, gcn2_w, gat1_w, gat2_w, gat1_as, gat1_ad, gat2_as, gat2_ad,
        wT1, wT2, wgT1, wgT2, was1, wad1, was2, wad2);
    scang1_kernel<<<GH / 256, 256, 0, stream>>>(ghist, gpre, gbsum, GH);
    bin_scatter_kernel<<<EBLK, 256, 0, stream>>>(esrc, edst, gpre, gbsum, ebuf);
    bucket_finalize_kernel<<<NBUK, 256, 0, stream>>>(ebuf, gpre, gbsum, rowptr, dinv, csrc);

    // ---- GCN1 ----
    mm2_kernel<IND, 3, true><<<GB, 256, 0, stream>>>(x, wT1, mmbf, nullptr, dinv, NN, 64);
    gcn_fused_kernel<<<NB, 256, 0, stream>>>(rowptr, csrc, dinv, mmbf,
        gcn1_b, bn1_g, bn1_b, bn1_m, bn1_v, actb);

    // ---- GAT1 (C=64) ----
    scores_kernel<<<NB, 256, 0, stream>>>(actb, was1, wad1, es, ed, NN);
    gat_agg_kernel<<<NB, 256, 0, stream>>>(rowptr, csrc, es, ed, actb, agg);
    mm2_kernel<512, 2, false><<<GB, 256, 0, stream>>>(agg, wgT1, actb, gat1_b, nullptr, NN, 64);

    // ---- GCN2 ----
    mm2_kernel<64, 3, false><<<GB, 256, 0, stream>>>(actb, wT2, mmbf, nullptr, dinv, NN, 64);
    gcn_fused_kernel<<<NB, 256, 0, stream>>>(rowptr, csrc, dinv, mmbf,
        gcn2_b, bn2_g, bn2_b, bn2_m, bn2_v, actb);

    // ---- GAT2 (C=32) + fused log_softmax -> out ----
    scores_kernel<<<NB, 256, 0, stream>>>(actb, was2, wad2, es, ed, NN);
    gat_agg_kernel<<<NB, 256, 0, stream>>>(rowptr, csrc, es, ed, actb, agg);
    mm2_kernel<512, 4, false><<<GB, 256, 0, stream>>>(agg, wgT2, out, gat2_b, nullptr, NN, 32);
}

// Round 3
// 368.160 us; speedup vs baseline: 1.0768x; 1.0768x over previous
//
#include <hip/hip_runtime.h>
#include <hip/hip_bf16.h>

#define NN 50000
#define NE 800000
#define IND 128
#define NH 8
#define EBLK 256          // binning blocks
#define EPB 3125          // NE / EBLK
#define NBUK 391          // buckets of 128 dst nodes
#define NBUKP 392         // padded (bucket 391 empty -> offset == NE)
#define GH (NBUKP * EBLK) // 100352
#define PREPB 308         // prep blocks: 78848 / 256

typedef __hip_bfloat16 bf16;
typedef __attribute__((ext_vector_type(8))) short short8;
typedef __attribute__((ext_vector_type(8))) __bf16 bf16x8;
typedef __attribute__((ext_vector_type(4))) float floatx4;
typedef __attribute__((ext_vector_type(2))) float floatx2;

static __device__ __forceinline__ short f2bf_bits(float f) {
    unsigned u = __float_as_uint(f);
    u = (u + 0x7fffu + ((u >> 16) & 1u)) >> 16;
    return (short)u;
}
static __device__ __forceinline__ float bf2f(bf16 v) { return __bfloat162float(v); }
static __device__ __forceinline__ floatx2 up2(unsigned av) {
    floatx2 r;
    r.x = __uint_as_float(av << 16);
    r.y = __uint_as_float(av & 0xffff0000u);
    return r;
}
static __device__ __forceinline__ unsigned pk2(float a, float b) {
    return (unsigned)(unsigned short)f2bf_bits(a) | ((unsigned)(unsigned short)f2bf_bits(b) << 16);
}

// exclusive scan of bsum[0..NBUKP) into gb[0..512); mirrors scang1's proven pattern
static __device__ __forceinline__ void scan_buckets(const int* __restrict__ bsum,
        int* sp, int* gb, int tid) {
    int v0 = (2 * tid < NBUKP) ? bsum[2 * tid] : 0;
    int v1 = (2 * tid + 1 < NBUKP) ? bsum[2 * tid + 1] : 0;
    int c = v0 + v1;
    sp[tid] = c; __syncthreads();
    int val = c;
#pragma unroll
    for (int off = 1; off < 256; off <<= 1) {
        int t = (tid >= off) ? sp[tid - off] : 0;
        __syncthreads();
        val += t; sp[tid] = val;
        __syncthreads();
    }
    int pex = val - c;
    gb[2 * tid] = pex;
    gb[2 * tid + 1] = pex + v0;
    __syncthreads();
}

// ---------------- merged: edge bin counting (blocks 0..255) + weight prep (blocks 256..563) ----
__global__ __launch_bounds__(256) void bin_count_prep_kernel(const int* __restrict__ edst,
        int* __restrict__ ghist,
        const float* __restrict__ gcn1_w, const float* __restrict__ gcn2_w,
        const float* __restrict__ gat1_w, const float* __restrict__ gat2_w,
        const float* __restrict__ as1, const float* __restrict__ ad1,
        const float* __restrict__ as2, const float* __restrict__ ad2,
        bf16* __restrict__ wT1, bf16* __restrict__ wT2,
        bf16* __restrict__ wgT1, bf16* __restrict__ wgT2,
        float* __restrict__ was1, float* __restrict__ wad1,
        float* __restrict__ was2, float* __restrict__ wad2) {
    __shared__ int hsh[NBUKP];
    const int tid = threadIdx.x;
    if (blockIdx.x < EBLK) {
        const int blk = blockIdx.x;
        for (int b = tid; b < NBUKP; b += 256) hsh[b] = 0;
        __syncthreads();
        const int e0 = blk * EPB;
        for (int e = e0 + tid; e < e0 + EPB; e += 256)
            atomicAdd(&hsh[edst[e] >> 7], 1);
        __syncthreads();
        for (int b = tid; b < NBUKP; b += 256)
            ghist[b * EBLK + blk] = hsh[b];
    } else {
        int idx = (blockIdx.x - EBLK) * 256 + tid;
        if (idx < 8192) {
            int m = idx >> 7, k = idx & 127;
            ((short*)wT1)[idx] = f2bf_bits(gcn1_w[(long)k * 64 + m]);
        } else if (idx < 12288) {
            int i = idx - 8192;
            int m = i >> 6, k = i & 63;
            ((short*)wT2)[i] = f2bf_bits(gcn2_w[(long)k * 64 + m]);
        } else if (idx < 45056) {
            int i = idx - 12288;
            int m = i >> 9, k = i & 511;
            int h = k >> 6, c = k & 63;
            ((short*)wgT1)[i] = f2bf_bits(gat1_w[(long)c * 512 + h * 64 + m]);
        } else if (idx < 77824) {
            int i = idx - 45056;
            int m = i >> 9, k = i & 511;
            int h = k >> 6, c = k & 63;
            ((short*)wgT2)[i] = (m < 32) ? f2bf_bits(gat2_w[(long)c * 256 + h * 32 + m]) : (short)0;
        } else if (idx < 78336) {
            int i = idx - 77824;
            int h = i >> 6, c = i & 63;
            const float* wrow = gat1_w + (long)c * 512 + h * 64;
            float s = 0.f, d = 0.f;
            for (int cc = 0; cc < 64; ++cc) {
                float w = wrow[cc];
                s += w * as1[h * 64 + cc];
                d += w * ad1[h * 64 + cc];
            }
            was1[i] = s; wad1[i] = d;
        } else if (idx < 78848) {
            int i = idx - 78336;
            int h = i >> 6, c = i & 63;
            const float* wrow = gat2_w + (long)c * 256 + h * 32;
            float s = 0.f, d = 0.f;
            for (int cc = 0; cc < 32; ++cc) {
                float w = wrow[cc];
                s += w * as2[h * 32 + cc];
                d += w * ad2[h * 32 + cc];
            }
            was2[i] = s; wad2[i] = d;
        }
    }
}

__global__ __launch_bounds__(256) void scang1_kernel(const int* __restrict__ src,
        int* __restrict__ pre, int* __restrict__ bsum, int n) {
    __shared__ int sh[256];
    const int tid = threadIdx.x;
    const int idx = blockIdx.x * 256 + tid;
    int c = (idx < n) ? src[idx] : 0;
    sh[tid] = c; __syncthreads();
    int val = c;
#pragma unroll
    for (int off = 1; off < 256; off <<= 1) {
        int t = (tid >= off) ? sh[tid - off] : 0;
        __syncthreads();
        val += t; sh[tid] = val;
        __syncthreads();
    }
    if (idx < n) pre[idx] = val - c;
    if (tid == 255) bsum[blockIdx.x] = val;
}

// bin_scatter inlines the bucket-level scan (scang2 kernel removed)
__global__ __launch_bounds__(256) void bin_scatter_kernel(const int* __restrict__ esrc,
        const int* __restrict__ edst, const int* __restrict__ gpre,
        const int* __restrict__ bsum, unsigned* __restrict__ ebuf) {
    __shared__ int cur[NBUKP];
    __shared__ int sp[256], gb[512];
    const int tid = threadIdx.x, blk = blockIdx.x;
    scan_buckets(bsum, sp, gb, tid);
    for (int b = tid; b < NBUKP; b += 256)
        cur[b] = gpre[b * EBLK + blk] + gb[b];
    __syncthreads();
    const int e0 = blk * EPB;
    for (int e = e0 + tid; e < e0 + EPB; e += 256) {
        int d = edst[e], s = esrc[e];
        int pos = atomicAdd(&cur[d >> 7], 1);
        ebuf[pos] = ((unsigned)(d & 127) << 16) | (unsigned)s;
    }
}

__global__ __launch_bounds__(256) void bucket_finalize_kernel(const unsigned* __restrict__ ebuf,
        const int* __restrict__ gpre, const int* __restrict__ bsum,
        int* __restrict__ rowptr, float* __restrict__ dinv, int* __restrict__ csrc) {
    __shared__ int lh[128], lcur[128], sc[256];
    __shared__ int sp[256], gb[512];
    const int bu = blockIdx.x, tid = threadIdx.x;
    scan_buckets(bsum, sp, gb, tid);
    const int seg_beg = gpre[bu * EBLK] + gb[bu];
    const int seg_end = gpre[(bu + 1) * EBLK] + gb[bu + 1];
    if (tid < 128) lh[tid] = 0;
    __syncthreads();
    for (int i = seg_beg + tid; i < seg_end; i += 256)
        atomicAdd(&lh[ebuf[i] >> 16], 1);
    __syncthreads();
    int c = (tid < 128) ? lh[tid] : 0;
    sc[tid] = c; __syncthreads();
    int val = c;
#pragma unroll
    for (int off = 1; off < 256; off <<= 1) {
        int t = (tid >= off) ? sc[tid - off] : 0;
        __syncthreads();
        val += t; sc[tid] = val;
        __syncthreads();
    }
    int excl = val - c;
    if (tid < 128) {
        lcur[tid] = excl;
        int node = bu * 128 + tid;
        if (node < NN) {
            rowptr[node] = seg_beg + excl;
            dinv[node] = rsqrtf((float)c + 1.f);
        }
    }
    if (bu == 0 && tid == 0) rowptr[NN] = NE;
    __syncthreads();
    for (int i = seg_beg + tid; i < seg_end; i += 256) {
        unsigned u = ebuf[i];
        int pos = atomicAdd(&lcur[u >> 16], 1);
        csrc[seg_beg + pos] = (int)(u & 0xffffu);
    }
}

// ---------------- MFMA matmul v2: NO LDS ----------------
template<int K, int EPI, bool AF32>
__global__ __launch_bounds__(256) void mm2_kernel(const void* __restrict__ A,
        const bf16* __restrict__ wT, void* __restrict__ C,
        const float* __restrict__ bias, const float* __restrict__ rowscale,
        int nrows, int M) {
    const int row0 = blockIdx.x * 64;
    const int tid = threadIdx.x;
    const int lane = tid & 63, wave = tid >> 6;
    const int lr = lane & 15, q = lane >> 4;
    const int row = row0 + wave * 16 + lr;
    const bool rok = row < nrows;
    constexpr int NC = (EPI == 4) ? 2 : 4;
    floatx4 acc[NC] = {};
#pragma unroll 4
    for (int k0 = 0; k0 < K; k0 += 32) {
        short8 av = {0, 0, 0, 0, 0, 0, 0, 0};
        if (rok) {
            if (AF32) {
                const float* apf = (const float*)A + (long)row * K + q * 8 + k0;
                floatx4 va = *(const floatx4*)apf;
                floatx4 vb = *(const floatx4*)(apf + 4);
#pragma unroll
                for (int j = 0; j < 4; ++j) { av[j] = f2bf_bits(va[j]); av[4 + j] = f2bf_bits(vb[j]); }
            } else {
                av = *(const short8*)((const short*)A + (long)row * K + q * 8 + k0);
            }
        }
        bf16x8 a = __builtin_bit_cast(bf16x8, av);
#pragma unroll
        for (int c = 0; c < NC; ++c) {
            bf16x8 b = __builtin_bit_cast(bf16x8,
                *(const short8*)((const short*)wT + (long)(c * 16 + lr) * K + k0 + q * 8));
            acc[c] = __builtin_amdgcn_mfma_f32_16x16x32_bf16(a, b, acc[c], 0, 0, 0);
        }
    }
    if (EPI == 4) {
#pragma unroll
        for (int r = 0; r < 4; ++r) {
            int orow = row0 + wave * 16 + q * 4 + r;
            float v0 = acc[0][r] * 0.125f + bias[lr];
            float v1 = acc[1][r] * 0.125f + bias[16 + lr];
            float m = fmaxf(v0, v1);
#pragma unroll
            for (int off = 1; off < 16; off <<= 1) m = fmaxf(m, __shfl_xor(m, off));
            float s = __expf(v0 - m) + __expf(v1 - m);
#pragma unroll
            for (int off = 1; off < 16; off <<= 1) s += __shfl_xor(s, off);
            float ls = m + logf(s);
            if (orow < nrows) {
                ((float*)C)[(long)orow * 32 + lr] = v0 - ls;
                ((float*)C)[(long)orow * 32 + 16 + lr] = v1 - ls;
            }
        }
        return;
    }
#pragma unroll
    for (int c = 0; c < NC; ++c)
#pragma unroll
        for (int r = 0; r < 4; ++r) {
            int orow = row0 + wave * 16 + q * 4 + r;
            int col = c * 16 + lr;
            if (orow < nrows && col < M) {
                long o = (long)orow * M + col;
                float v = acc[c][r];
                if (EPI == 0) ((float*)C)[o] = v;
                else if (EPI == 2) {
                    v = v * 0.125f + bias[col];
                    ((bf16*)C)[o] = __float2bfloat16(fmaxf(v, 0.f));
                } else {
                    ((bf16*)C)[o] = __float2bfloat16(rowscale[orow] * v);
                }
            }
        }
}

// ---------------- fused GCN aggregate + bias + BN + ReLU (8-deep batched gather) ----------------
__global__ __launch_bounds__(256) void gcn_fused_kernel(const int* __restrict__ rowptr,
        const int* __restrict__ csrc, const float* __restrict__ dinv,
        const bf16* __restrict__ hin, const float* __restrict__ b,
        const float* __restrict__ gamma, const float* __restrict__ beta,
        const float* __restrict__ mean, const float* __restrict__ var,
        bf16* __restrict__ actout) {
    const int node = blockIdx.x * 4 + (threadIdx.x >> 6);
    if (node >= NN) return;
    const int lane = threadIdx.x & 63;
    const int eslot = lane >> 5, cp = lane & 31;
    const unsigned cpo = 4u * (unsigned)cp;
    const int beg = rowptr[node], end = rowptr[node + 1];
    const float di = dinv[node];
    floatx2 acc2 = {0.f, 0.f};
    const int kup = ((end - beg) + 15) & ~15;
    for (int k0 = 0; k0 < kup; k0 += 16) {
        int s_[8]; float w_[8];
#pragma unroll
        for (int u = 0; u < 8; ++u) {
            int ei = beg + k0 + 2 * u + eslot;
            int ok = ei < end;
            s_[u] = csrc[ok ? ei : beg];
            w_[u] = ok ? 1.f : 0.f;
        }
        unsigned av_[8];
#pragma unroll
        for (int u = 0; u < 8; ++u)
            av_[u] = *(const unsigned*)((const char*)hin + ((unsigned)s_[u] * 128u + cpo));
#pragma unroll
        for (int u = 0; u < 8; ++u) {
            floatx2 a2 = up2(av_[u]);
            acc2 += a2 * w_[u];
        }
    }
    acc2.x += __shfl_xor(acc2.x, 32);
    acc2.y += __shfl_xor(acc2.y, 32);
    {
        unsigned sv = *(const unsigned*)((const char*)hin + ((unsigned)node * 128u + cpo));
        acc2 += up2(sv);
    }
    int c0 = 2 * cp, c1 = c0 + 1;
    float x0 = acc2.x * di + b[c0];
    float x1 = acc2.y * di + b[c1];
    x0 = (x0 - mean[c0]) * rsqrtf(var[c0] + 1e-5f) * gamma[c0] + beta[c0];
    x1 = (x1 - mean[c1]) * rsqrtf(var[c1] + 1e-5f) * gamma[c1] + beta[c1];
    if (eslot == 0)
        *(unsigned*)((unsigned short*)actout + (long)node * 64 + c0) =
            pk2(fmaxf(x0, 0.f), fmaxf(x1, 0.f));
}

// es[n,h] = <act[n,:], was[h,:]>
__global__ __launch_bounds__(256) void scores_kernel(const bf16* __restrict__ actb,
        const float* __restrict__ was, const float* __restrict__ wad,
        float* __restrict__ es, float* __restrict__ ed, int n) {
    const int node = blockIdx.x * 4 + (threadIdx.x >> 6);
    if (node >= n) return;
    const int lane = threadIdx.x & 63;
    const int h = lane >> 3, cg = lane & 7;
    short8 a8 = *(const short8*)((const short*)actb + (long)node * 64 + cg * 8);
    const float* wsp = was + h * 64 + cg * 8;
    const float* wdp = wad + h * 64 + cg * 8;
    floatx4 ws0 = *(const floatx4*)wsp, ws1 = *(const floatx4*)(wsp + 4);
    floatx4 wd0 = *(const floatx4*)wdp, wd1 = *(const floatx4*)(wdp + 4);
    float s = 0.f, d = 0.f;
#pragma unroll
    for (int j = 0; j < 4; ++j) {
        float v0 = bf2f(__builtin_bit_cast(bf16, a8[j]));
        float v1 = bf2f(__builtin_bit_cast(bf16, a8[4 + j]));
        s += v0 * ws0[j] + v1 * ws1[j];
        d += v0 * wd0[j] + v1 * wd1[j];
    }
#pragma unroll
    for (int off = 1; off < 8; off <<= 1) {
        s += __shfl_xor(s, off);
        d += __shfl_xor(d, off);
    }
    if (cg == 0) { es[node * NH + h] = s; ed[node * NH + h] = d; }
}

// ---------------- GAT aggregation (self-shifted softmax), MLP-pipelined ----------------
// Phase A (R1 lineage): independent clamped gathers; wave-uniform skip of dead 8-edge blocks.
// Phase B: 8-edge groups, 2-deep software pipeline with NAMED register banks — group g+1's
//          8 row-loads are issued before group g's FMAs, so up to 16 gathers are in flight
//          and a deg-16 node pays ~1 exposed gather-latency stall instead of 4.
__global__ __launch_bounds__(256) void gat_agg_kernel(const int* __restrict__ rowptr,
        const int* __restrict__ csrc, const float* __restrict__ es, const float* __restrict__ ed,
        const bf16* __restrict__ actb, bf16* __restrict__ agg) {
    __shared__ __align__(16) float salpha[4][512];
    __shared__ int ssrcs[4][64];
    __shared__ __align__(16) float sself[4][8];
    const int wv = threadIdx.x >> 6;
    const int node = blockIdx.x * 4 + wv;
    if (node >= NN) return;
    const int lane = threadIdx.x & 63;
    const int h = lane & 7, slot = lane >> 3;
    const int beg = rowptr[node], end = rowptr[node + 1];
    const int deg = end - beg;
    const float edr = *(const float*)((const char*)ed + ((unsigned)node * 32u + (unsigned)h * 4u));

    float selfe = *(const float*)((const char*)es + ((unsigned)node * 32u + (unsigned)h * 4u)) + edr;
    selfe = selfe > 0.f ? selfe : 0.2f * selfe;

    if (deg <= 64) {
        // ---- Phase A: independent clamped gathers, uniform-branch block skip ----
        const int nb = (deg + 7) >> 3;           // live 8-edge blocks (wave-uniform)
        const int dm1 = (deg > 0) ? deg - 1 : 0;
        float ex_r[8]; int s_r[8];
        float den = 0.f;
#pragma unroll
        for (int b = 0; b < 8; ++b) { ex_r[b] = 0.f; s_r[b] = 0; }
        if (deg > 0) {
#pragma unroll
            for (int b = 0; b < 8; ++b)
                if (b < nb) {                    // wave-uniform
                    int k = b * 8 + slot;
                    s_r[b] = csrc[beg + (k < deg ? k : dm1)];
                }
#pragma unroll
            for (int b = 0; b < 8; ++b)
                if (b < nb) {
                    float e = *(const float*)((const char*)es +
                              ((unsigned)s_r[b] * 32u + (unsigned)h * 4u)) + edr;
                    e = e > 0.f ? e : 0.2f * e;
                    float ex = __expf(e - selfe);
                    ex_r[b] = (b * 8 + slot < deg) ? ex : 0.f;
                    den += ex_r[b];
                }
        }
        den += __shfl_xor(den, 8);
        den += __shfl_xor(den, 16);
        den += __shfl_xor(den, 32);
        const float invden = 1.f / (den + 1.f);

        // stage alphas (alpha(k,h) at salpha[(k>>3)*64 + (k&7)*8 + h]) + srcs + self
#pragma unroll
        for (int b = 0; b < 8; ++b)
            if (b < nb) salpha[wv][b * 64 + lane] = ex_r[b] * invden;
        if (h == 0) {
#pragma unroll
            for (int b = 0; b < 8; ++b)
                if (b < nb) ssrcs[wv][b * 8 + slot] = s_r[b];
        }
        if (slot == 0) sself[wv][h] = invden;

        // ---- Phase B: (head-quad, channel-pair) gather, pipelined 8-edge groups ----
        const int hq = lane >> 5, cp = lane & 31;
        const unsigned cpo = 4u * (unsigned)cp;
        floatx2 acc2[4] = {};
        const int ng = nb;                        // groups of 8 edges
        if (ng > 0) {
            int sA0, sA1, sA2, sA3, sA4, sA5, sA6, sA7;
            int sB0, sB1, sB2, sB3, sB4, sB5, sB6, sB7;
            unsigned rA0, rA1, rA2, rA3, rA4, rA5, rA6, rA7;
            unsigned rB0, rB1, rB2, rB3, rB4, rB5, rB6, rB7;
#define LOAD_BANK(S, R, G) do { \
    const int* sp_ = &ssrcs[wv][(G) * 8]; \
    S##0 = sp_[0]; S##1 = sp_[1]; S##2 = sp_[2]; S##3 = sp_[3]; \
    S##4 = sp_[4]; S##5 = sp_[5]; S##6 = sp_[6]; S##7 = sp_[7]; \
    R##0 = *(const unsigned*)((const char*)actb + ((unsigned)S##0 * 128u + cpo)); \
    R##1 = *(const unsigned*)((const char*)actb + ((unsigned)S##1 * 128u + cpo)); \
    R##2 = *(const unsigned*)((const char*)actb + ((unsigned)S##2 * 128u + cpo)); \
    R##3 = *(const unsigned*)((const char*)actb + ((unsigned)S##3 * 128u + cpo)); \
    R##4 = *(const unsigned*)((const char*)actb + ((unsigned)S##4 * 128u + cpo)); \
    R##5 = *(const unsigned*)((const char*)actb + ((unsigned)S##5 * 128u + cpo)); \
    R##6 = *(const unsigned*)((const char*)actb + ((unsigned)S##6 * 128u + cpo)); \
    R##7 = *(const unsigned*)((const char*)actb + ((unsigned)S##7 * 128u + cpo)); \
} while (0)
#define FMA_BANK(R, G) do { \
    const float* ab_ = &salpha[wv][(G) * 64 + hq * 4]; \
    unsigned rr_[8] = {R##0, R##1, R##2, R##3, R##4, R##5, R##6, R##7}; \
    _Pragma("unroll") \
    for (int j_ = 0; j_ < 8; ++j_) { \
        floatx4 al_ = *(const floatx4*)(ab_ + j_ * 8); \
        floatx2 a2_ = up2(rr_[j_]); \
        acc2[0] += a2_ * al_[0]; acc2[1] += a2_ * al_[1]; \
        acc2[2] += a2_ * al_[2]; acc2[3] += a2_ * al_[3]; \
    } \
} while (0)
            LOAD_BANK(sA, rA, 0);
            int g = 0;
            while (true) {
                if (g + 1 < ng) LOAD_BANK(sB, rB, g + 1);
                FMA_BANK(rA, g);
                ++g; if (g >= ng) break;
                if (g + 1 < ng) LOAD_BANK(sA, rA, g + 1);
                FMA_BANK(rB, g);
                ++g; if (g >= ng) break;
            }
#undef LOAD_BANK
#undef FMA_BANK
        }
        {   // self edge
            unsigned sv = *(const unsigned*)((const char*)actb + ((unsigned)node * 128u + cpo));
            floatx2 a2 = up2(sv);
            floatx4 sa = *(const floatx4*)&sself[wv][hq * 4];
            acc2[0] += a2 * sa[0]; acc2[1] += a2 * sa[1];
            acc2[2] += a2 * sa[2]; acc2[3] += a2 * sa[3];
        }
#pragma unroll
        for (int j = 0; j < 4; ++j)
            *(unsigned*)((unsigned short*)agg + (long)node * 512 + (hq * 4 + j) * 64 + 2 * cp) =
                pk2(acc2[j].x, acc2[j].y);
    } else {
        // ---- fallback (deg>64, rare): streaming two-pass, full-wave per edge ----
        float acc[NH] = {0.f, 0.f, 0.f, 0.f, 0.f, 0.f, 0.f, 0.f};
        float den = 0.f;
        for (int base = beg; base < end; base += 8) {
            int ei = base + slot;
            if (ei < end) {
                int s = csrc[ei];
                float e = es[s * NH + h] + edr;
                e = e > 0.f ? e : 0.2f * e;
                den += __expf(e - selfe);
            }
        }
        den += __shfl_xor(den, 8);
        den += __shfl_xor(den, 16);
        den += __shfl_xor(den, 32);
        const float invden = 1.f / (den + 1.f);
        for (int base = beg; base < end; base += 8) {
            int ei = base + slot;
            float al = 0.f; int sl = 0;
            if (ei < end) {
                sl = csrc[ei];
                float e = es[sl * NH + h] + edr;
                e = e > 0.f ? e : 0.2f * e;
                al = __expf(e - selfe) * invden;
            }
            salpha[wv][lane] = al;
            if (h == 0) ssrcs[wv][slot] = sl;
            int ecnt = end - base; if (ecnt > 8) ecnt = 8;
            for (int j = 0; j < ecnt; ++j) {
                int s = ssrcs[wv][j];
                float a = bf2f(actb[(long)s * 64 + lane]);
                floatx4 al0 = *(const floatx4*)&salpha[wv][j * 8];
                floatx4 al1 = *(const floatx4*)&salpha[wv][j * 8 + 4];
                acc[0] += al0[0] * a; acc[1] += al0[1] * a;
                acc[2] += al0[2] * a; acc[3] += al0[3] * a;
                acc[4] += al1[0] * a; acc[5] += al1[1] * a;
                acc[6] += al1[2] * a; acc[7] += al1[3] * a;
            }
        }
        {
            if (slot == 0) sself[wv][h] = invden;
            float a = bf2f(actb[(long)node * 64 + lane]);
            floatx4 s0 = *(const floatx4*)&sself[wv][0];
            floatx4 s1 = *(const floatx4*)&sself[wv][4];
            acc[0] += s0[0] * a; acc[1] += s0[1] * a;
            acc[2] += s0[2] * a; acc[3] += s0[3] * a;
            acc[4] += s1[0] * a; acc[5] += s1[1] * a;
            acc[6] += s1[2] * a; acc[7] += s1[3] * a;
        }
#pragma unroll
        for (int hh = 0; hh < NH; ++hh)
            agg[(long)node * 512 + hh * 64 + lane] = __float2bfloat16(acc[hh]);
    }
}

// ---------------- launch ----------------
extern "C" void kernel_launch(void* const* d_in, const int* in_sizes, int n_in,
                              void* d_out, int out_size, void* d_ws, size_t ws_size,
                              hipStream_t stream) {
    const float* x        = (const float*)d_in[0];
    const int*   eidx     = (const int*)d_in[1];
    const float* gcn1_w   = (const float*)d_in[2];
    const float* gcn1_b   = (const float*)d_in[3];
    const float* bn1_g    = (const float*)d_in[4];
    const float* bn1_b    = (const float*)d_in[5];
    const float* bn1_m    = (const float*)d_in[6];
    const float* bn1_v    = (const float*)d_in[7];
    const float* gat1_w   = (const float*)d_in[8];
    const float* gat1_as  = (const float*)d_in[9];
    const float* gat1_ad  = (const float*)d_in[10];
    const float* gat1_b   = (const float*)d_in[11];
    const float* gcn2_w   = (const float*)d_in[12];
    const float* gcn2_b   = (const float*)d_in[13];
    const float* bn2_g    = (const float*)d_in[14];
    const float* bn2_b    = (const float*)d_in[15];
    const float* bn2_m    = (const float*)d_in[16];
    const float* bn2_v    = (const float*)d_in[17];
    const float* gat2_w   = (const float*)d_in[18];
    const float* gat2_as  = (const float*)d_in[19];
    const float* gat2_ad  = (const float*)d_in[20];
    const float* gat2_b   = (const float*)d_in[21];
    float* out = (float*)d_out;

    const int* esrc = eidx;
    const int* edst = eidx + NE;

    // workspace (~78 MB, < proven-safe 110.6 MB)
    float* ws = (float*)d_ws;
    int*      ghist  = (int*)ws;                        // GH
    int*      gpre   = ghist + GH;                      // GH
    int*      gbsum  = gpre + GH;                       // 512 (unscanned block sums)
    unsigned* ebuf   = (unsigned*)(gbsum + 512);        // NE
    int*      rowptr = (int*)(ebuf + NE);               // 50048
    int*      csrc   = rowptr + 50048;                  // NE
    float*    dinv   = (float*)(csrc + NE);             // 50048
    float*    es     = dinv + 50048;                    // 400000
    float*    ed     = es + 400000;                     // 400000
    float*    was1   = ed + 400000;                     // 512
    float*    wad1   = was1 + 512;                      // 512
    float*    was2   = wad1 + 512;                      // 512
    float*    wad2   = was2 + 512;                      // 512
    bf16*     wT1    = (bf16*)(wad2 + 512);             // 64*128
    bf16*     wT2    = wT1 + 64 * 128;                  // 64*64
    bf16*     wgT1   = wT2 + 64 * 64;                   // 64*512
    bf16*     wgT2   = wgT1 + 64 * 512;                 // 64*512
    bf16*     actb   = wgT2 + 64 * 512;                 // N*64 bf16
    bf16*     mmbf   = actb + (size_t)NN * 64;          // N*64 bf16
    bf16*     agg    = mmbf + (size_t)NN * 64;          // N*512 bf16

    auto cdiv = [](long a, long b) { return (int)((a + b - 1) / b); };
    const int GB = cdiv(NN, 64);
    const int NB = cdiv(NN, 4);

    // ---- CSR build ----
    bin_count_prep_kernel<<<EBLK + PREPB, 256, 0, stream>>>(edst, ghist,
        gcn1_w, gcn2_w, gat1_w, gat2_w, gat1_as, gat1_ad, gat2_as, gat2_ad,
        wT1, wT2, wgT1, wgT2, was1, wad1, was2, wad2);
    scang1_kernel<<<GH / 256, 256, 0, stream>>>(ghist, gpre, gbsum, GH);
    bin_scatter_kernel<<<EBLK, 256, 0, stream>>>(esrc, edst, gpre, gbsum, ebuf);
    bucket_finalize_kernel<<<NBUK, 256, 0, stream>>>(ebuf, gpre, gbsum, rowptr, dinv, csrc);

    // ---- GCN1 ----
    mm2_kernel<IND, 3, true><<<GB, 256, 0, stream>>>(x, wT1, mmbf, nullptr, dinv, NN, 64);
    gcn_fused_kernel<<<NB, 256, 0, stream>>>(rowptr, csrc, dinv, mmbf,
        gcn1_b, bn1_g, bn1_b, bn1_m, bn1_v, actb);

    // ---- GAT1 (C=64) ----
    scores_kernel<<<NB, 256, 0, stream>>>(actb, was1, wad1, es, ed, NN);
    gat_agg_kernel<<<NB, 256, 0, stream>>>(rowptr, csrc, es, ed, actb, agg);
    mm2_kernel<512, 2, false><<<GB, 256, 0, stream>>>(agg, wgT1, actb, gat1_b, nullptr, NN, 64);

    // ---- GCN2 ----
    mm2_kernel<64, 3, false><<<GB, 256, 0, stream>>>(actb, wT2, mmbf, nullptr, dinv, NN, 64);
    gcn_fused_kernel<<<NB, 256, 0, stream>>>(rowptr, csrc, dinv, mmbf,
        gcn2_b, bn2_g, bn2_b, bn2_m, bn2_v, actb);

    // ---- GAT2 (C=32) + fused log_softmax -> out ----
    scores_kernel<<<NB, 256, 0, stream>>>(actb, was2, wad2, es, ed, NN);
    gat_agg_kernel<<<NB, 256, 0, stream>>>(rowptr, csrc, es, ed, actb, agg);
    mm2_kernel<512, 4, false><<<GB, 256, 0, stream>>>(agg, wgT2, out, gat2_b, nullptr, NN, 32);
}

// Round 4
// 363.991 us; speedup vs baseline: 1.0891x; 1.0115x over previous
//
#include <hip/hip_runtime.h>
#include <hip/hip_bf16.h>

#define NN 50000
#define NE 800000
#define IND 128
#define NH 8
#define EBLK 256          // binning blocks
#define EPB 3125          // NE / EBLK
#define NBUK 391          // buckets of 128 dst nodes
#define NBUKP 392         // padded (bucket 391 empty -> offset == NE)
#define GH (NBUKP * EBLK) // 100352
#define PREPB 308         // prep blocks: 78848 / 256

typedef __hip_bfloat16 bf16;
typedef __attribute__((ext_vector_type(8))) short short8;
typedef __attribute__((ext_vector_type(8))) __bf16 bf16x8;
typedef __attribute__((ext_vector_type(4))) float floatx4;
typedef __attribute__((ext_vector_type(2))) float floatx2;

static __device__ __forceinline__ short f2bf_bits(float f) {
    unsigned u = __float_as_uint(f);
    u = (u + 0x7fffu + ((u >> 16) & 1u)) >> 16;
    return (short)u;
}
static __device__ __forceinline__ float bf2f(bf16 v) { return __bfloat162float(v); }
static __device__ __forceinline__ floatx2 up2(unsigned av) {
    floatx2 r;
    r.x = __uint_as_float(av << 16);
    r.y = __uint_as_float(av & 0xffff0000u);
    return r;
}
static __device__ __forceinline__ unsigned pk2(float a, float b) {
    return (unsigned)(unsigned short)f2bf_bits(a) | ((unsigned)(unsigned short)f2bf_bits(b) << 16);
}
// acc.lo += a.lo * al.lo ; acc.hi += a.hi * al.lo   (broadcast LOW half of al)
static __device__ __forceinline__ void pk_fma_lo(floatx2& acc, floatx2 a, floatx2 al) {
    asm("v_pk_fma_f32 %0, %1, %2, %0 op_sel:[0,0,0] op_sel_hi:[1,0,1]"
        : "+v"(acc) : "v"(a), "v"(al));
}
// acc.lo += a.lo * al.hi ; acc.hi += a.hi * al.hi   (broadcast HIGH half of al)
static __device__ __forceinline__ void pk_fma_hi(floatx2& acc, floatx2 a, floatx2 al) {
    asm("v_pk_fma_f32 %0, %1, %2, %0 op_sel:[0,1,0] op_sel_hi:[1,1,1]"
        : "+v"(acc) : "v"(a), "v"(al));
}

// exclusive scan of bsum[0..NBUKP) into gb[0..512); mirrors scang1's proven pattern
static __device__ __forceinline__ void scan_buckets(const int* __restrict__ bsum,
        int* sp, int* gb, int tid) {
    int v0 = (2 * tid < NBUKP) ? bsum[2 * tid] : 0;
    int v1 = (2 * tid + 1 < NBUKP) ? bsum[2 * tid + 1] : 0;
    int c = v0 + v1;
    sp[tid] = c; __syncthreads();
    int val = c;
#pragma unroll
    for (int off = 1; off < 256; off <<= 1) {
        int t = (tid >= off) ? sp[tid - off] : 0;
        __syncthreads();
        val += t; sp[tid] = val;
        __syncthreads();
    }
    int pex = val - c;
    gb[2 * tid] = pex;
    gb[2 * tid + 1] = pex + v0;
    __syncthreads();
}

// ---------------- merged: edge bin counting (blocks 0..255) + weight prep (blocks 256..563) ----
__global__ __launch_bounds__(256) void bin_count_prep_kernel(const int* __restrict__ edst,
        int* __restrict__ ghist,
        const float* __restrict__ gcn1_w, const float* __restrict__ gcn2_w,
        const float* __restrict__ gat1_w, const float* __restrict__ gat2_w,
        const float* __restrict__ as1, const float* __restrict__ ad1,
        const float* __restrict__ as2, const float* __restrict__ ad2,
        bf16* __restrict__ wT1, bf16* __restrict__ wT2,
        bf16* __restrict__ wgT1, bf16* __restrict__ wgT2,
        float* __restrict__ was1, float* __restrict__ wad1,
        float* __restrict__ was2, float* __restrict__ wad2) {
    __shared__ int hsh[NBUKP];
    const int tid = threadIdx.x;
    if (blockIdx.x < EBLK) {
        const int blk = blockIdx.x;
        for (int b = tid; b < NBUKP; b += 256) hsh[b] = 0;
        __syncthreads();
        const int e0 = blk * EPB;
        for (int e = e0 + tid; e < e0 + EPB; e += 256)
            atomicAdd(&hsh[edst[e] >> 7], 1);
        __syncthreads();
        for (int b = tid; b < NBUKP; b += 256)
            ghist[b * EBLK + blk] = hsh[b];
    } else {
        int idx = (blockIdx.x - EBLK) * 256 + tid;
        if (idx < 8192) {
            int m = idx >> 7, k = idx & 127;
            ((short*)wT1)[idx] = f2bf_bits(gcn1_w[(long)k * 64 + m]);
        } else if (idx < 12288) {
            int i = idx - 8192;
            int m = i >> 6, k = i & 63;
            ((short*)wT2)[i] = f2bf_bits(gcn2_w[(long)k * 64 + m]);
        } else if (idx < 45056) {
            int i = idx - 12288;
            int m = i >> 9, k = i & 511;
            int h = k >> 6, c = k & 63;
            ((short*)wgT1)[i] = f2bf_bits(gat1_w[(long)c * 512 + h * 64 + m]);
        } else if (idx < 77824) {
            int i = idx - 45056;
            int m = i >> 9, k = i & 511;
            int h = k >> 6, c = k & 63;
            ((short*)wgT2)[i] = (m < 32) ? f2bf_bits(gat2_w[(long)c * 256 + h * 32 + m]) : (short)0;
        } else if (idx < 78336) {
            int i = idx - 77824;
            int h = i >> 6, c = i & 63;
            const float* wrow = gat1_w + (long)c * 512 + h * 64;
            float s = 0.f, d = 0.f;
            for (int cc = 0; cc < 64; ++cc) {
                float w = wrow[cc];
                s += w * as1[h * 64 + cc];
                d += w * ad1[h * 64 + cc];
            }
            was1[i] = s; wad1[i] = d;
        } else if (idx < 78848) {
            int i = idx - 78336;
            int h = i >> 6, c = i & 63;
            const float* wrow = gat2_w + (long)c * 256 + h * 32;
            float s = 0.f, d = 0.f;
            for (int cc = 0; cc < 32; ++cc) {
                float w = wrow[cc];
                s += w * as2[h * 32 + cc];
                d += w * ad2[h * 32 + cc];
            }
            was2[i] = s; wad2[i] = d;
        }
    }
}

__global__ __launch_bounds__(256) void scang1_kernel(const int* __restrict__ src,
        int* __restrict__ pre, int* __restrict__ bsum, int n) {
    __shared__ int sh[256];
    const int tid = threadIdx.x;
    const int idx = blockIdx.x * 256 + tid;
    int c = (idx < n) ? src[idx] : 0;
    sh[tid] = c; __syncthreads();
    int val = c;
#pragma unroll
    for (int off = 1; off < 256; off <<= 1) {
        int t = (tid >= off) ? sh[tid - off] : 0;
        __syncthreads();
        val += t; sh[tid] = val;
        __syncthreads();
    }
    if (idx < n) pre[idx] = val - c;
    if (tid == 255) bsum[blockIdx.x] = val;
}

// bin_scatter inlines the bucket-level scan (scang2 kernel removed)
__global__ __launch_bounds__(256) void bin_scatter_kernel(const int* __restrict__ esrc,
        const int* __restrict__ edst, const int* __restrict__ gpre,
        const int* __restrict__ bsum, unsigned* __restrict__ ebuf) {
    __shared__ int cur[NBUKP];
    __shared__ int sp[256], gb[512];
    const int tid = threadIdx.x, blk = blockIdx.x;
    scan_buckets(bsum, sp, gb, tid);
    for (int b = tid; b < NBUKP; b += 256)
        cur[b] = gpre[b * EBLK + blk] + gb[b];
    __syncthreads();
    const int e0 = blk * EPB;
    for (int e = e0 + tid; e < e0 + EPB; e += 256) {
        int d = edst[e], s = esrc[e];
        int pos = atomicAdd(&cur[d >> 7], 1);
        ebuf[pos] = ((unsigned)(d & 127) << 16) | (unsigned)s;
    }
}

__global__ __launch_bounds__(256) void bucket_finalize_kernel(const unsigned* __restrict__ ebuf,
        const int* __restrict__ gpre, const int* __restrict__ bsum,
        int* __restrict__ rowptr, float* __restrict__ dinv, int* __restrict__ csrc) {
    __shared__ int lh[128], lcur[128], sc[256];
    __shared__ int sp[256], gb[512];
    const int bu = blockIdx.x, tid = threadIdx.x;
    scan_buckets(bsum, sp, gb, tid);
    const int seg_beg = gpre[bu * EBLK] + gb[bu];
    const int seg_end = gpre[(bu + 1) * EBLK] + gb[bu + 1];
    if (tid < 128) lh[tid] = 0;
    __syncthreads();
    for (int i = seg_beg + tid; i < seg_end; i += 256)
        atomicAdd(&lh[ebuf[i] >> 16], 1);
    __syncthreads();
    int c = (tid < 128) ? lh[tid] : 0;
    sc[tid] = c; __syncthreads();
    int val = c;
#pragma unroll
    for (int off = 1; off < 256; off <<= 1) {
        int t = (tid >= off) ? sc[tid - off] : 0;
        __syncthreads();
        val += t; sc[tid] = val;
        __syncthreads();
    }
    int excl = val - c;
    if (tid < 128) {
        lcur[tid] = excl;
        int node = bu * 128 + tid;
        if (node < NN) {
            rowptr[node] = seg_beg + excl;
            dinv[node] = rsqrtf((float)c + 1.f);
        }
    }
    if (bu == 0 && tid == 0) rowptr[NN] = NE;
    __syncthreads();
    for (int i = seg_beg + tid; i < seg_end; i += 256) {
        unsigned u = ebuf[i];
        int pos = atomicAdd(&lcur[u >> 16], 1);
        csrc[seg_beg + pos] = (int)(u & 0xffffu);
    }
}

// ---------------- MFMA matmul v2: NO LDS ----------------
template<int K, int EPI, bool AF32>
__global__ __launch_bounds__(256) void mm2_kernel(const void* __restrict__ A,
        const bf16* __restrict__ wT, void* __restrict__ C,
        const float* __restrict__ bias, const float* __restrict__ rowscale,
        int nrows, int M) {
    const int row0 = blockIdx.x * 64;
    const int tid = threadIdx.x;
    const int lane = tid & 63, wave = tid >> 6;
    const int lr = lane & 15, q = lane >> 4;
    const int row = row0 + wave * 16 + lr;
    const bool rok = row < nrows;
    constexpr int NC = (EPI == 4) ? 2 : 4;
    floatx4 acc[NC] = {};
#pragma unroll 4
    for (int k0 = 0; k0 < K; k0 += 32) {
        short8 av = {0, 0, 0, 0, 0, 0, 0, 0};
        if (rok) {
            if (AF32) {
                const float* apf = (const float*)A + (long)row * K + q * 8 + k0;
                floatx4 va = *(const floatx4*)apf;
                floatx4 vb = *(const floatx4*)(apf + 4);
#pragma unroll
                for (int j = 0; j < 4; ++j) { av[j] = f2bf_bits(va[j]); av[4 + j] = f2bf_bits(vb[j]); }
            } else {
                av = *(const short8*)((const short*)A + (long)row * K + q * 8 + k0);
            }
        }
        bf16x8 a = __builtin_bit_cast(bf16x8, av);
#pragma unroll
        for (int c = 0; c < NC; ++c) {
            bf16x8 b = __builtin_bit_cast(bf16x8,
                *(const short8*)((const short*)wT + (long)(c * 16 + lr) * K + k0 + q * 8));
            acc[c] = __builtin_amdgcn_mfma_f32_16x16x32_bf16(a, b, acc[c], 0, 0, 0);
        }
    }
    if (EPI == 4) {
#pragma unroll
        for (int r = 0; r < 4; ++r) {
            int orow = row0 + wave * 16 + q * 4 + r;
            float v0 = acc[0][r] * 0.125f + bias[lr];
            float v1 = acc[1][r] * 0.125f + bias[16 + lr];
            float m = fmaxf(v0, v1);
#pragma unroll
            for (int off = 1; off < 16; off <<= 1) m = fmaxf(m, __shfl_xor(m, off));
            float s = __expf(v0 - m) + __expf(v1 - m);
#pragma unroll
            for (int off = 1; off < 16; off <<= 1) s += __shfl_xor(s, off);
            float ls = m + logf(s);
            if (orow < nrows) {
                ((float*)C)[(long)orow * 32 + lr] = v0 - ls;
                ((float*)C)[(long)orow * 32 + 16 + lr] = v1 - ls;
            }
        }
        return;
    }
#pragma unroll
    for (int c = 0; c < NC; ++c)
#pragma unroll
        for (int r = 0; r < 4; ++r) {
            int orow = row0 + wave * 16 + q * 4 + r;
            int col = c * 16 + lr;
            if (orow < nrows && col < M) {
                long o = (long)orow * M + col;
                float v = acc[c][r];
                if (EPI == 0) ((float*)C)[o] = v;
                else if (EPI == 2) {
                    v = v * 0.125f + bias[col];
                    ((bf16*)C)[o] = __float2bfloat16(fmaxf(v, 0.f));
                } else {
                    ((bf16*)C)[o] = __float2bfloat16(rowscale[orow] * v);
                }
            }
        }
}

// ---------------- fused GCN aggregate + bias + BN + ReLU (8-deep batched gather) ----------------
__global__ __launch_bounds__(256) void gcn_fused_kernel(const int* __restrict__ rowptr,
        const int* __restrict__ csrc, const float* __restrict__ dinv,
        const bf16* __restrict__ hin, const float* __restrict__ b,
        const float* __restrict__ gamma, const float* __restrict__ beta,
        const float* __restrict__ mean, const float* __restrict__ var,
        bf16* __restrict__ actout) {
    const int node = blockIdx.x * 4 + (threadIdx.x >> 6);
    if (node >= NN) return;
    const int lane = threadIdx.x & 63;
    const int eslot = lane >> 5, cp = lane & 31;
    const unsigned cpo = 4u * (unsigned)cp;
    // wave-uniform scalars -> SALU control flow + SGPR load bases
    const int beg = __builtin_amdgcn_readfirstlane(rowptr[node]);
    const int end = __builtin_amdgcn_readfirstlane(rowptr[node + 1]);
    const float di = dinv[node];
    const int* csp = csrc + beg;
    floatx2 acc2 = {0.f, 0.f};
    const int dn = end - beg;
    const int kup = (dn + 15) & ~15;
    for (int k0 = 0; k0 < kup; k0 += 16) {
        int s_[8]; float w_[8];
#pragma unroll
        for (int u = 0; u < 8; ++u) {
            int k = k0 + 2 * u + eslot;
            int ok = k < dn;
            s_[u] = csp[ok ? k : 0];
            w_[u] = ok ? 1.f : 0.f;
        }
        unsigned av_[8];
#pragma unroll
        for (int u = 0; u < 8; ++u)
            av_[u] = *(const unsigned*)((const char*)hin + ((unsigned)s_[u] * 128u + cpo));
#pragma unroll
        for (int u = 0; u < 8; ++u) {
            floatx2 a2 = up2(av_[u]);
            acc2 += a2 * w_[u];
        }
    }
    acc2.x += __shfl_xor(acc2.x, 32);
    acc2.y += __shfl_xor(acc2.y, 32);
    {
        unsigned sv = *(const unsigned*)((const char*)hin + ((unsigned)node * 128u + cpo));
        acc2 += up2(sv);
    }
    int c0 = 2 * cp, c1 = c0 + 1;
    float x0 = acc2.x * di + b[c0];
    float x1 = acc2.y * di + b[c1];
    x0 = (x0 - mean[c0]) * rsqrtf(var[c0] + 1e-5f) * gamma[c0] + beta[c0];
    x1 = (x1 - mean[c1]) * rsqrtf(var[c1] + 1e-5f) * gamma[c1] + beta[c1];
    if (eslot == 0)
        *(unsigned*)((unsigned short*)actout + (long)node * 64 + c0) =
            pk2(fmaxf(x0, 0.f), fmaxf(x1, 0.f));
}

// es[n,h] = <act[n,:], was[h,:]>
__global__ __launch_bounds__(256) void scores_kernel(const bf16* __restrict__ actb,
        const float* __restrict__ was, const float* __restrict__ wad,
        float* __restrict__ es, float* __restrict__ ed, int n) {
    const int node = blockIdx.x * 4 + (threadIdx.x >> 6);
    if (node >= n) return;
    const int lane = threadIdx.x & 63;
    const int h = lane >> 3, cg = lane & 7;
    short8 a8 = *(const short8*)((const short*)actb + (long)node * 64 + cg * 8);
    const float* wsp = was + h * 64 + cg * 8;
    const float* wdp = wad + h * 64 + cg * 8;
    floatx4 ws0 = *(const floatx4*)wsp, ws1 = *(const floatx4*)(wsp + 4);
    floatx4 wd0 = *(const floatx4*)wdp, wd1 = *(const floatx4*)(wdp + 4);
    float s = 0.f, d = 0.f;
#pragma unroll
    for (int j = 0; j < 4; ++j) {
        float v0 = bf2f(__builtin_bit_cast(bf16, a8[j]));
        float v1 = bf2f(__builtin_bit_cast(bf16, a8[4 + j]));
        s += v0 * ws0[j] + v1 * ws1[j];
        d += v0 * wd0[j] + v1 * wd1[j];
    }
#pragma unroll
    for (int off = 1; off < 8; off <<= 1) {
        s += __shfl_xor(s, off);
        d += __shfl_xor(d, off);
    }
    if (cg == 0) { es[node * NH + h] = s; ed[node * NH + h] = d; }
}

// ---------------- GAT aggregation (self-shifted softmax), pk_fma + scalarized ----------------
// Phase A (R3 lineage): independent clamped gathers; SALU-uniform skip of dead 8-edge blocks.
// Phase B: 8-edge groups, 2-deep pipeline with named register banks; per-edge math uses
//          v_pk_fma_f32 with op_sel broadcast (4 pk_fma replace 8 v_fma per edge).
__global__ __launch_bounds__(256) void gat_agg_kernel(const int* __restrict__ rowptr,
        const int* __restrict__ csrc, const float* __restrict__ es, const float* __restrict__ ed,
        const bf16* __restrict__ actb, bf16* __restrict__ agg) {
    __shared__ __align__(16) float salpha[4][512];
    __shared__ int ssrcs[4][64];
    __shared__ __align__(16) float sself[4][8];
    const int wv = threadIdx.x >> 6;
    const int node = blockIdx.x * 4 + wv;
    if (node >= NN) return;
    const int lane = threadIdx.x & 63;
    const int h = lane & 7, slot = lane >> 3;
    // wave-uniform scalars
    const int beg = __builtin_amdgcn_readfirstlane(rowptr[node]);
    const int end = __builtin_amdgcn_readfirstlane(rowptr[node + 1]);
    const int deg = end - beg;
    const int* csp = csrc + beg;
    const float edr = *(const float*)((const char*)ed + ((unsigned)node * 32u + (unsigned)h * 4u));

    float selfe = *(const float*)((const char*)es + ((unsigned)node * 32u + (unsigned)h * 4u)) + edr;
    selfe = selfe > 0.f ? selfe : 0.2f * selfe;

    if (deg <= 64) {
        // ---- Phase A: independent clamped gathers, uniform-branch block skip ----
        const int nb = (deg + 7) >> 3;           // live 8-edge blocks (SGPR)
        const int dm1 = (deg > 0) ? deg - 1 : 0;
        float ex_r[8]; int s_r[8];
        float den = 0.f;
#pragma unroll
        for (int b = 0; b < 8; ++b) { ex_r[b] = 0.f; s_r[b] = 0; }
        if (deg > 0) {
#pragma unroll
            for (int b = 0; b < 8; ++b)
                if (b < nb) {
                    int k = b * 8 + slot;
                    s_r[b] = csp[k < deg ? k : dm1];
                }
#pragma unroll
            for (int b = 0; b < 8; ++b)
                if (b < nb) {
                    float e = *(const float*)((const char*)es +
                              ((unsigned)s_r[b] * 32u + (unsigned)h * 4u)) + edr;
                    e = e > 0.f ? e : 0.2f * e;
                    float ex = __expf(e - selfe);
                    ex_r[b] = (b * 8 + slot < deg) ? ex : 0.f;
                    den += ex_r[b];
                }
        }
        den += __shfl_xor(den, 8);
        den += __shfl_xor(den, 16);
        den += __shfl_xor(den, 32);
        const float invden = 1.f / (den + 1.f);

        // stage alphas (alpha(k,h) at salpha[(k>>3)*64 + (k&7)*8 + h]) + srcs + self
#pragma unroll
        for (int b = 0; b < 8; ++b)
            if (b < nb) salpha[wv][b * 64 + lane] = ex_r[b] * invden;
        if (h == 0) {
#pragma unroll
            for (int b = 0; b < 8; ++b)
                if (b < nb) ssrcs[wv][b * 8 + slot] = s_r[b];
        }
        if (slot == 0) sself[wv][h] = invden;

        // ---- Phase B: (head-quad, channel-pair) gather, pipelined 8-edge groups ----
        const int hq = lane >> 5, cp = lane & 31;
        const unsigned cpo = 4u * (unsigned)cp;
        floatx2 acc2[4] = {};
        const int ng = nb;                        // groups of 8 edges
        if (ng > 0) {
            int sA0, sA1, sA2, sA3, sA4, sA5, sA6, sA7;
            int sB0, sB1, sB2, sB3, sB4, sB5, sB6, sB7;
            unsigned rA0, rA1, rA2, rA3, rA4, rA5, rA6, rA7;
            unsigned rB0, rB1, rB2, rB3, rB4, rB5, rB6, rB7;
#define LOAD_BANK(S, R, G) do { \
    const int* sp_ = &ssrcs[wv][(G) * 8]; \
    S##0 = sp_[0]; S##1 = sp_[1]; S##2 = sp_[2]; S##3 = sp_[3]; \
    S##4 = sp_[4]; S##5 = sp_[5]; S##6 = sp_[6]; S##7 = sp_[7]; \
    R##0 = *(const unsigned*)((const char*)actb + ((unsigned)S##0 * 128u + cpo)); \
    R##1 = *(const unsigned*)((const char*)actb + ((unsigned)S##1 * 128u + cpo)); \
    R##2 = *(const unsigned*)((const char*)actb + ((unsigned)S##2 * 128u + cpo)); \
    R##3 = *(const unsigned*)((const char*)actb + ((unsigned)S##3 * 128u + cpo)); \
    R##4 = *(const unsigned*)((const char*)actb + ((unsigned)S##4 * 128u + cpo)); \
    R##5 = *(const unsigned*)((const char*)actb + ((unsigned)S##5 * 128u + cpo)); \
    R##6 = *(const unsigned*)((const char*)actb + ((unsigned)S##6 * 128u + cpo)); \
    R##7 = *(const unsigned*)((const char*)actb + ((unsigned)S##7 * 128u + cpo)); \
} while (0)
#define FMA_BANK(R, G) do { \
    const float* ab_ = &salpha[wv][(G) * 64 + hq * 4]; \
    unsigned rr_[8] = {R##0, R##1, R##2, R##3, R##4, R##5, R##6, R##7}; \
    _Pragma("unroll") \
    for (int j_ = 0; j_ < 8; ++j_) { \
        floatx4 al_ = *(const floatx4*)(ab_ + j_ * 8); \
        floatx2 al01_ = __builtin_shufflevector(al_, al_, 0, 1); \
        floatx2 al23_ = __builtin_shufflevector(al_, al_, 2, 3); \
        floatx2 a2_ = up2(rr_[j_]); \
        pk_fma_lo(acc2[0], a2_, al01_); pk_fma_hi(acc2[1], a2_, al01_); \
        pk_fma_lo(acc2[2], a2_, al23_); pk_fma_hi(acc2[3], a2_, al23_); \
    } \
} while (0)
            LOAD_BANK(sA, rA, 0);
            int g = 0;
            while (true) {
                if (g + 1 < ng) LOAD_BANK(sB, rB, g + 1);
                FMA_BANK(rA, g);
                ++g; if (g >= ng) break;
                if (g + 1 < ng) LOAD_BANK(sA, rA, g + 1);
                FMA_BANK(rB, g);
                ++g; if (g >= ng) break;
            }
#undef LOAD_BANK
#undef FMA_BANK
        }
        {   // self edge
            unsigned sv = *(const unsigned*)((const char*)actb + ((unsigned)node * 128u + cpo));
            floatx2 a2 = up2(sv);
            floatx4 sa = *(const floatx4*)&sself[wv][hq * 4];
            floatx2 sa01 = __builtin_shufflevector(sa, sa, 0, 1);
            floatx2 sa23 = __builtin_shufflevector(sa, sa, 2, 3);
            pk_fma_lo(acc2[0], a2, sa01); pk_fma_hi(acc2[1], a2, sa01);
            pk_fma_lo(acc2[2], a2, sa23); pk_fma_hi(acc2[3], a2, sa23);
        }
#pragma unroll
        for (int j = 0; j < 4; ++j)
            *(unsigned*)((unsigned short*)agg + (long)node * 512 + (hq * 4 + j) * 64 + 2 * cp) =
                pk2(acc2[j].x, acc2[j].y);
    } else {
        // ---- fallback (deg>64, rare): streaming two-pass, full-wave per edge ----
        float acc[NH] = {0.f, 0.f, 0.f, 0.f, 0.f, 0.f, 0.f, 0.f};
        float den = 0.f;
        for (int base = beg; base < end; base += 8) {
            int ei = base + slot;
            if (ei < end) {
                int s = csrc[ei];
                float e = es[s * NH + h] + edr;
                e = e > 0.f ? e : 0.2f * e;
                den += __expf(e - selfe);
            }
        }
        den += __shfl_xor(den, 8);
        den += __shfl_xor(den, 16);
        den += __shfl_xor(den, 32);
        const float invden = 1.f / (den + 1.f);
        for (int base = beg; base < end; base += 8) {
            int ei = base + slot;
            float al = 0.f; int sl = 0;
            if (ei < end) {
                sl = csrc[ei];
                float e = es[sl * NH + h] + edr;
                e = e > 0.f ? e : 0.2f * e;
                al = __expf(e - selfe) * invden;
            }
            salpha[wv][lane] = al;
            if (h == 0) ssrcs[wv][slot] = sl;
            int ecnt = end - base; if (ecnt > 8) ecnt = 8;
            for (int j = 0; j < ecnt; ++j) {
                int s = ssrcs[wv][j];
                float a = bf2f(actb[(long)s * 64 + lane]);
                floatx4 al0 = *(const floatx4*)&salpha[wv][j * 8];
                floatx4 al1 = *(const floatx4*)&salpha[wv][j * 8 + 4];
                acc[0] += al0[0] * a; acc[1] += al0[1] * a;
                acc[2] += al0[2] * a; acc[3] += al0[3] * a;
                acc[4] += al1[0] * a; acc[5] += al1[1] * a;
                acc[6] += al1[2] * a; acc[7] += al1[3] * a;
            }
        }
        {
            if (slot == 0) sself[wv][h] = invden;
            float a = bf2f(actb[(long)node * 64 + lane]);
            floatx4 s0 = *(const floatx4*)&sself[wv][0];
            floatx4 s1 = *(const floatx4*)&sself[wv][4];
            acc[0] += s0[0] * a; acc[1] += s0[1] * a;
            acc[2] += s0[2] * a; acc[3] += s0[3] * a;
            acc[4] += s1[0] * a; acc[5] += s1[1] * a;
            acc[6] += s1[2] * a; acc[7] += s1[3] * a;
        }
#pragma unroll
        for (int hh = 0; hh < NH; ++hh)
            agg[(long)node * 512 + hh * 64 + lane] = __float2bfloat16(acc[hh]);
    }
}

// ---------------- launch ----------------
extern "C" void kernel_launch(void* const* d_in, const int* in_sizes, int n_in,
                              void* d_out, int out_size, void* d_ws, size_t ws_size,
                              hipStream_t stream) {
    const float* x        = (const float*)d_in[0];
    const int*   eidx     = (const int*)d_in[1];
    const float* gcn1_w   = (const float*)d_in[2];
    const float* gcn1_b   = (const float*)d_in[3];
    const float* bn1_g    = (const float*)d_in[4];
    const float* bn1_b    = (const float*)d_in[5];
    const float* bn1_m    = (const float*)d_in[6];
    const float* bn1_v    = (const float*)d_in[7];
    const float* gat1_w   = (const float*)d_in[8];
    const float* gat1_as  = (const float*)d_in[9];
    const float* gat1_ad  = (const float*)d_in[10];
    const float* gat1_b   = (const float*)d_in[11];
    const float* gcn2_w   = (const float*)d_in[12];
    const float* gcn2_b   = (const float*)d_in[13];
    const float* bn2_g    = (const float*)d_in[14];
    const float* bn2_b    = (const float*)d_in[15];
    const float* bn2_m    = (const float*)d_in[16];
    const float* bn2_v    = (const float*)d_in[17];
    const float* gat2_w   = (const float*)d_in[18];
    const float* gat2_as  = (const float*)d_in[19];
    const float* gat2_ad  = (const float*)d_in[20];
    const float* gat2_b   = (const float*)d_in[21];
    float* out = (float*)d_out;

    const int* esrc = eidx;
    const int* edst = eidx + NE;

    // workspace (~78 MB, < proven-safe 110.6 MB)
    float* ws = (float*)d_ws;
    int*      ghist  = (int*)ws;                        // GH
    int*      gpre   = ghist + GH;                      // GH
    int*      gbsum  = gpre + GH;                       // 512 (unscanned block sums)
    unsigned* ebuf   = (unsigned*)(gbsum + 512);        // NE
    int*      rowptr = (int*)(ebuf + NE);               // 50048
    int*      csrc   = rowptr + 50048;                  // NE
    float*    dinv   = (float*)(csrc + NE);             // 50048
    float*    es     = dinv + 50048;                    // 400000
    float*    ed     = es + 400000;                     // 400000
    float*    was1   = ed + 400000;                     // 512
    float*    wad1   = was1 + 512;                      // 512
    float*    was2   = wad1 + 512;                      // 512
    float*    wad2   = was2 + 512;                      // 512
    bf16*     wT1    = (bf16*)(wad2 + 512);             // 64*128
    bf16*     wT2    = wT1 + 64 * 128;                  // 64*64
    bf16*     wgT1   = wT2 + 64 * 64;                   // 64*512
    bf16*     wgT2   = wgT1 + 64 * 512;                 // 64*512
    bf16*     actb   = wgT2 + 64 * 512;                 // N*64 bf16
    bf16*     mmbf   = actb + (size_t)NN * 64;          // N*64 bf16
    bf16*     agg    = mmbf + (size_t)NN * 64;          // N*512 bf16

    auto cdiv = [](long a, long b) { return (int)((a + b - 1) / b); };
    const int GB = cdiv(NN, 64);
    const int NB = cdiv(NN, 4);

    // ---- CSR build ----
    bin_count_prep_kernel<<<EBLK + PREPB, 256, 0, stream>>>(edst, ghist,
        gcn1_w, gcn2_w, gat1_w, gat2_w, gat1_as, gat1_ad, gat2_as, gat2_ad,
        wT1, wT2, wgT1, wgT2, was1, wad1, was2, wad2);
    scang1_kernel<<<GH / 256, 256, 0, stream>>>(ghist, gpre, gbsum, GH);
    bin_scatter_kernel<<<EBLK, 256, 0, stream>>>(esrc, edst, gpre, gbsum, ebuf);
    bucket_finalize_kernel<<<NBUK, 256, 0, stream>>>(ebuf, gpre, gbsum, rowptr, dinv, csrc);

    // ---- GCN1 ----
    mm2_kernel<IND, 3, true><<<GB, 256, 0, stream>>>(x, wT1, mmbf, nullptr, dinv, NN, 64);
    gcn_fused_kernel<<<NB, 256, 0, stream>>>(rowptr, csrc, dinv, mmbf,
        gcn1_b, bn1_g, bn1_b, bn1_m, bn1_v, actb);

    // ---- GAT1 (C=64) ----
    scores_kernel<<<NB, 256, 0, stream>>>(actb, was1, wad1, es, ed, NN);
    gat_agg_kernel<<<NB, 256, 0, stream>>>(rowptr, csrc, es, ed, actb, agg);
    mm2_kernel<512, 2, false><<<GB, 256, 0, stream>>>(agg, wgT1, actb, gat1_b, nullptr, NN, 64);

    // ---- GCN2 ----
    mm2_kernel<64, 3, false><<<GB, 256, 0, stream>>>(actb, wT2, mmbf, nullptr, dinv, NN, 64);
    gcn_fused_kernel<<<NB, 256, 0, stream>>>(rowptr, csrc, dinv, mmbf,
        gcn2_b, bn2_g, bn2_b, bn2_m, bn2_v, actb);

    // ---- GAT2 (C=32) + fused log_softmax -> out ----
    scores_kernel<<<NB, 256, 0, stream>>>(actb, was2, wad2, es, ed, NN);
    gat_agg_kernel<<<NB, 256, 0, stream>>>(rowptr, csrc, es, ed, actb, agg);
    mm2_kernel<512, 4, false><<<GB, 256, 0, stream>>>(agg, wgT2, out, gat2_b, nullptr, NN, 32);
}

// Round 5
// 347.569 us; speedup vs baseline: 1.1406x; 1.0472x over previous
//
#include <hip/hip_runtime.h>
#include <hip/hip_bf16.h>

#define NN 50000
#define NE 800000
#define IND 128
#define NH 8
#define EBLK 256          // binning blocks
#define EPB 3125          // NE / EBLK
#define NBUK 391          // buckets of 128 dst nodes
#define NBUKP 392         // padded (bucket 391 empty -> offset == NE)
#define GH (NBUKP * EBLK) // 100352
#define PREPB 308         // prep blocks: 78848 / 256

typedef __hip_bfloat16 bf16;
typedef __attribute__((ext_vector_type(8))) short short8;
typedef __attribute__((ext_vector_type(8))) __bf16 bf16x8;
typedef __attribute__((ext_vector_type(4))) float floatx4;
typedef __attribute__((ext_vector_type(2))) float floatx2;

static __device__ __forceinline__ short f2bf_bits(float f) {
    unsigned u = __float_as_uint(f);
    u = (u + 0x7fffu + ((u >> 16) & 1u)) >> 16;
    return (short)u;
}
static __device__ __forceinline__ float bf2f(bf16 v) { return __bfloat162float(v); }
static __device__ __forceinline__ floatx2 up2(unsigned av) {
    floatx2 r;
    r.x = __uint_as_float(av << 16);
    r.y = __uint_as_float(av & 0xffff0000u);
    return r;
}
static __device__ __forceinline__ unsigned pk2(float a, float b) {
    return (unsigned)(unsigned short)f2bf_bits(a) | ((unsigned)(unsigned short)f2bf_bits(b) << 16);
}
// acc.lo += a.lo * al.lo ; acc.hi += a.hi * al.lo   (broadcast LOW half of al)
static __device__ __forceinline__ void pk_fma_lo(floatx2& acc, floatx2 a, floatx2 al) {
    asm("v_pk_fma_f32 %0, %1, %2, %0 op_sel:[0,0,0] op_sel_hi:[1,0,1]"
        : "+v"(acc) : "v"(a), "v"(al));
}
// acc.lo += a.lo * al.hi ; acc.hi += a.hi * al.hi   (broadcast HIGH half of al)
static __device__ __forceinline__ void pk_fma_hi(floatx2& acc, floatx2 a, floatx2 al) {
    asm("v_pk_fma_f32 %0, %1, %2, %0 op_sel:[0,1,0] op_sel_hi:[1,1,1]"
        : "+v"(acc) : "v"(a), "v"(al));
}

// exclusive scan of bsum[0..NBUKP) into gb[0..512); mirrors scang1's proven pattern
static __device__ __forceinline__ void scan_buckets(const int* __restrict__ bsum,
        int* sp, int* gb, int tid) {
    int v0 = (2 * tid < NBUKP) ? bsum[2 * tid] : 0;
    int v1 = (2 * tid + 1 < NBUKP) ? bsum[2 * tid + 1] : 0;
    int c = v0 + v1;
    sp[tid] = c; __syncthreads();
    int val = c;
#pragma unroll
    for (int off = 1; off < 256; off <<= 1) {
        int t = (tid >= off) ? sp[tid - off] : 0;
        __syncthreads();
        val += t; sp[tid] = val;
        __syncthreads();
    }
    int pex = val - c;
    gb[2 * tid] = pex;
    gb[2 * tid + 1] = pex + v0;
    __syncthreads();
}

// ---------------- merged: edge bin counting (blocks 0..255) + weight prep (blocks 256..563) ----
__global__ __launch_bounds__(256) void bin_count_prep_kernel(const int* __restrict__ edst,
        int* __restrict__ ghist,
        const float* __restrict__ gcn1_w, const float* __restrict__ gcn2_w,
        const float* __restrict__ gat1_w, const float* __restrict__ gat2_w,
        const float* __restrict__ as1, const float* __restrict__ ad1,
        const float* __restrict__ as2, const float* __restrict__ ad2,
        bf16* __restrict__ wT1, bf16* __restrict__ wT2,
        bf16* __restrict__ wgT1, bf16* __restrict__ wgT2,
        float* __restrict__ was1, float* __restrict__ wad1,
        float* __restrict__ was2, float* __restrict__ wad2) {
    __shared__ int hsh[NBUKP];
    const int tid = threadIdx.x;
    if (blockIdx.x < EBLK) {
        const int blk = blockIdx.x;
        for (int b = tid; b < NBUKP; b += 256) hsh[b] = 0;
        __syncthreads();
        const int e0 = blk * EPB;
        for (int e = e0 + tid; e < e0 + EPB; e += 256)
            atomicAdd(&hsh[edst[e] >> 7], 1);
        __syncthreads();
        for (int b = tid; b < NBUKP; b += 256)
            ghist[b * EBLK + blk] = hsh[b];
    } else {
        int idx = (blockIdx.x - EBLK) * 256 + tid;
        if (idx < 8192) {
            int m = idx >> 7, k = idx & 127;
            ((short*)wT1)[idx] = f2bf_bits(gcn1_w[(long)k * 64 + m]);
        } else if (idx < 12288) {
            int i = idx - 8192;
            int m = i >> 6, k = i & 63;
            ((short*)wT2)[i] = f2bf_bits(gcn2_w[(long)k * 64 + m]);
        } else if (idx < 45056) {
            int i = idx - 12288;
            int m = i >> 9, k = i & 511;
            int h = k >> 6, c = k & 63;
            ((short*)wgT1)[i] = f2bf_bits(gat1_w[(long)c * 512 + h * 64 + m]);
        } else if (idx < 77824) {
            int i = idx - 45056;
            int m = i >> 9, k = i & 511;
            int h = k >> 6, c = k & 63;
            ((short*)wgT2)[i] = (m < 32) ? f2bf_bits(gat2_w[(long)c * 256 + h * 32 + m]) : (short)0;
        } else if (idx < 78336) {
            int i = idx - 77824;
            int h = i >> 6, c = i & 63;
            const float* wrow = gat1_w + (long)c * 512 + h * 64;
            float s = 0.f, d = 0.f;
            for (int cc = 0; cc < 64; ++cc) {
                float w = wrow[cc];
                s += w * as1[h * 64 + cc];
                d += w * ad1[h * 64 + cc];
            }
            was1[i] = s; wad1[i] = d;
        } else if (idx < 78848) {
            int i = idx - 78336;
            int h = i >> 6, c = i & 63;
            const float* wrow = gat2_w + (long)c * 256 + h * 32;
            float s = 0.f, d = 0.f;
            for (int cc = 0; cc < 32; ++cc) {
                float w = wrow[cc];
                s += w * as2[h * 32 + cc];
                d += w * ad2[h * 32 + cc];
            }
            was2[i] = s; wad2[i] = d;
        }
    }
}

__global__ __launch_bounds__(256) void scang1_kernel(const int* __restrict__ src,
        int* __restrict__ pre, int* __restrict__ bsum, int n) {
    __shared__ int sh[256];
    const int tid = threadIdx.x;
    const int idx = blockIdx.x * 256 + tid;
    int c = (idx < n) ? src[idx] : 0;
    sh[tid] = c; __syncthreads();
    int val = c;
#pragma unroll
    for (int off = 1; off < 256; off <<= 1) {
        int t = (tid >= off) ? sh[tid - off] : 0;
        __syncthreads();
        val += t; sh[tid] = val;
        __syncthreads();
    }
    if (idx < n) pre[idx] = val - c;
    if (tid == 255) bsum[blockIdx.x] = val;
}

// bin_scatter inlines the bucket-level scan (scang2 kernel removed)
__global__ __launch_bounds__(256) void bin_scatter_kernel(const int* __restrict__ esrc,
        const int* __restrict__ edst, const int* __restrict__ gpre,
        const int* __restrict__ bsum, unsigned* __restrict__ ebuf) {
    __shared__ int cur[NBUKP];
    __shared__ int sp[256], gb[512];
    const int tid = threadIdx.x, blk = blockIdx.x;
    scan_buckets(bsum, sp, gb, tid);
    for (int b = tid; b < NBUKP; b += 256)
        cur[b] = gpre[b * EBLK + blk] + gb[b];
    __syncthreads();
    const int e0 = blk * EPB;
    for (int e = e0 + tid; e < e0 + EPB; e += 256) {
        int d = edst[e], s = esrc[e];
        int pos = atomicAdd(&cur[d >> 7], 1);
        ebuf[pos] = ((unsigned)(d & 127) << 16) | (unsigned)s;
    }
}

__global__ __launch_bounds__(256) void bucket_finalize_kernel(const unsigned* __restrict__ ebuf,
        const int* __restrict__ gpre, const int* __restrict__ bsum,
        int* __restrict__ rowptr, float* __restrict__ dinv, int* __restrict__ csrc) {
    __shared__ int lh[128], lcur[128], sc[256];
    __shared__ int sp[256], gb[512];
    const int bu = blockIdx.x, tid = threadIdx.x;
    scan_buckets(bsum, sp, gb, tid);
    const int seg_beg = gpre[bu * EBLK] + gb[bu];
    const int seg_end = gpre[(bu + 1) * EBLK] + gb[bu + 1];
    if (tid < 128) lh[tid] = 0;
    __syncthreads();
    for (int i = seg_beg + tid; i < seg_end; i += 256)
        atomicAdd(&lh[ebuf[i] >> 16], 1);
    __syncthreads();
    int c = (tid < 128) ? lh[tid] : 0;
    sc[tid] = c; __syncthreads();
    int val = c;
#pragma unroll
    for (int off = 1; off < 256; off <<= 1) {
        int t = (tid >= off) ? sc[tid - off] : 0;
        __syncthreads();
        val += t; sc[tid] = val;
        __syncthreads();
    }
    int excl = val - c;
    if (tid < 128) {
        lcur[tid] = excl;
        int node = bu * 128 + tid;
        if (node < NN) {
            rowptr[node] = seg_beg + excl;
            dinv[node] = rsqrtf((float)c + 1.f);
        }
    }
    if (bu == 0 && tid == 0) rowptr[NN] = NE;
    __syncthreads();
    for (int i = seg_beg + tid; i < seg_end; i += 256) {
        unsigned u = ebuf[i];
        int pos = atomicAdd(&lcur[u >> 16], 1);
        csrc[seg_beg + pos] = (int)(u & 0xffffu);
    }
}

// ---------------- MFMA matmul v2: NO LDS ----------------
template<int K, int EPI, bool AF32>
__global__ __launch_bounds__(256) void mm2_kernel(const void* __restrict__ A,
        const bf16* __restrict__ wT, void* __restrict__ C,
        const float* __restrict__ bias, const float* __restrict__ rowscale,
        int nrows, int M) {
    const int row0 = blockIdx.x * 64;
    const int tid = threadIdx.x;
    const int lane = tid & 63, wave = tid >> 6;
    const int lr = lane & 15, q = lane >> 4;
    const int row = row0 + wave * 16 + lr;
    const bool rok = row < nrows;
    constexpr int NC = 4;
    floatx4 acc[NC] = {};
#pragma unroll 4
    for (int k0 = 0; k0 < K; k0 += 32) {
        short8 av = {0, 0, 0, 0, 0, 0, 0, 0};
        if (rok) {
            if (AF32) {
                const float* apf = (const float*)A + (long)row * K + q * 8 + k0;
                floatx4 va = *(const floatx4*)apf;
                floatx4 vb = *(const floatx4*)(apf + 4);
#pragma unroll
                for (int j = 0; j < 4; ++j) { av[j] = f2bf_bits(va[j]); av[4 + j] = f2bf_bits(vb[j]); }
            } else {
                av = *(const short8*)((const short*)A + (long)row * K + q * 8 + k0);
            }
        }
        bf16x8 a = __builtin_bit_cast(bf16x8, av);
#pragma unroll
        for (int c = 0; c < NC; ++c) {
            bf16x8 b = __builtin_bit_cast(bf16x8,
                *(const short8*)((const short*)wT + (long)(c * 16 + lr) * K + k0 + q * 8));
            acc[c] = __builtin_amdgcn_mfma_f32_16x16x32_bf16(a, b, acc[c], 0, 0, 0);
        }
    }
#pragma unroll
    for (int c = 0; c < NC; ++c)
#pragma unroll
        for (int r = 0; r < 4; ++r) {
            int orow = row0 + wave * 16 + q * 4 + r;
            int col = c * 16 + lr;
            if (orow < nrows && col < M) {
                long o = (long)orow * M + col;
                float v = acc[c][r];
                if (EPI == 0) ((float*)C)[o] = v;
                else if (EPI == 2) {
                    v = v * 0.125f + bias[col];
                    ((bf16*)C)[o] = __float2bfloat16(fmaxf(v, 0.f));
                } else {
                    ((bf16*)C)[o] = __float2bfloat16(rowscale[orow] * v);
                }
            }
        }
}

// ---------------- fused GCN aggregate + bias + BN + ReLU (8-deep batched gather) ----------------
__global__ __launch_bounds__(256) void gcn_fused_kernel(const int* __restrict__ rowptr,
        const int* __restrict__ csrc, const float* __restrict__ dinv,
        const bf16* __restrict__ hin, const float* __restrict__ b,
        const float* __restrict__ gamma, const float* __restrict__ beta,
        const float* __restrict__ mean, const float* __restrict__ var,
        bf16* __restrict__ actout) {
    const int node = blockIdx.x * 4 + (threadIdx.x >> 6);
    if (node >= NN) return;
    const int lane = threadIdx.x & 63;
    const int eslot = lane >> 5, cp = lane & 31;
    const unsigned cpo = 4u * (unsigned)cp;
    const int beg = __builtin_amdgcn_readfirstlane(rowptr[node]);
    const int end = __builtin_amdgcn_readfirstlane(rowptr[node + 1]);
    const float di = dinv[node];
    const int* csp = csrc + beg;
    floatx2 acc2 = {0.f, 0.f};
    const int dn = end - beg;
    const int kup = (dn + 15) & ~15;
    for (int k0 = 0; k0 < kup; k0 += 16) {
        int s_[8]; float w_[8];
#pragma unroll
        for (int u = 0; u < 8; ++u) {
            int k = k0 + 2 * u + eslot;
            int ok = k < dn;
            s_[u] = csp[ok ? k : 0];
            w_[u] = ok ? 1.f : 0.f;
        }
        unsigned av_[8];
#pragma unroll
        for (int u = 0; u < 8; ++u)
            av_[u] = *(const unsigned*)((const char*)hin + ((unsigned)s_[u] * 128u + cpo));
#pragma unroll
        for (int u = 0; u < 8; ++u) {
            floatx2 a2 = up2(av_[u]);
            acc2 += a2 * w_[u];
        }
    }
    acc2.x += __shfl_xor(acc2.x, 32);
    acc2.y += __shfl_xor(acc2.y, 32);
    {
        unsigned sv = *(const unsigned*)((const char*)hin + ((unsigned)node * 128u + cpo));
        acc2 += up2(sv);
    }
    int c0 = 2 * cp, c1 = c0 + 1;
    float x0 = acc2.x * di + b[c0];
    float x1 = acc2.y * di + b[c1];
    x0 = (x0 - mean[c0]) * rsqrtf(var[c0] + 1e-5f) * gamma[c0] + beta[c0];
    x1 = (x1 - mean[c1]) * rsqrtf(var[c1] + 1e-5f) * gamma[c1] + beta[c1];
    if (eslot == 0)
        *(unsigned*)((unsigned short*)actout + (long)node * 64 + c0) =
            pk2(fmaxf(x0, 0.f), fmaxf(x1, 0.f));
}

// es[n,h] = <act[n,:], was[h,:]>
__global__ __launch_bounds__(256) void scores_kernel(const bf16* __restrict__ actb,
        const float* __restrict__ was, const float* __restrict__ wad,
        float* __restrict__ es, float* __restrict__ ed, int n) {
    const int node = blockIdx.x * 4 + (threadIdx.x >> 6);
    if (node >= n) return;
    const int lane = threadIdx.x & 63;
    const int h = lane >> 3, cg = lane & 7;
    short8 a8 = *(const short8*)((const short*)actb + (long)node * 64 + cg * 8);
    const float* wsp = was + h * 64 + cg * 8;
    const float* wdp = wad + h * 64 + cg * 8;
    floatx4 ws0 = *(const floatx4*)wsp, ws1 = *(const floatx4*)(wsp + 4);
    floatx4 wd0 = *(const floatx4*)wdp, wd1 = *(const floatx4*)(wdp + 4);
    float s = 0.f, d = 0.f;
#pragma unroll
    for (int j = 0; j < 4; ++j) {
        float v0 = bf2f(__builtin_bit_cast(bf16, a8[j]));
        float v1 = bf2f(__builtin_bit_cast(bf16, a8[4 + j]));
        s += v0 * ws0[j] + v1 * ws1[j];
        d += v0 * wd0[j] + v1 * wd1[j];
    }
#pragma unroll
    for (int off = 1; off < 8; off <<= 1) {
        s += __shfl_xor(s, off);
        d += __shfl_xor(d, off);
    }
    if (cg == 0) { es[node * NH + h] = s; ed[node * NH + h] = d; }
}

// ---------------- FUSED GAT: aggregation (LDS) + MFMA projection + epilogue ----------------
// 16 nodes/block (50000 = 3125*16 exact). Each wave aggregates 4 nodes into LDS aggt[16][520],
// then handles one 16-col tile of the [16x512]@[512x64] projection with 16 MFMAs.
// NCT: col-tiles (4 -> M=64 GAT1; 2 -> M=32 GAT2). EPI: 2 = bias+relu bf16; 4 = bias+logsoftmax f32.
template<int NCT, int EPI>
__global__ __launch_bounds__(256) void gat_fused_kernel(const int* __restrict__ rowptr,
        const int* __restrict__ csrc, const float* __restrict__ es, const float* __restrict__ ed,
        const bf16* __restrict__ actb, const bf16* __restrict__ wgT,
        const float* __restrict__ bias, void* __restrict__ outp) {
    __shared__ __align__(16) float salpha[4][512];
    __shared__ int ssrcs[4][64];
    __shared__ __align__(16) float sself[4][8];
    __shared__ __align__(16) unsigned short aggt[16][520];   // 520 = 512 + 8 pad (bank spread)
    __shared__ float redbuf[2][2][16];                        // [max|sum][ct][row]
    const int wv = threadIdx.x >> 6;
    const int lane = threadIdx.x & 63;
    const int h = lane & 7, slot = lane >> 3;
    const int hq = lane >> 5, cp = lane & 31;
    const unsigned cpo = 4u * (unsigned)cp;

    // ================= aggregation: 4 nodes per wave =================
#pragma unroll 1
    for (int nn = 0; nn < 4; ++nn) {
        const int row = wv * 4 + nn;
        const int node = blockIdx.x * 16 + row;
        const int beg = __builtin_amdgcn_readfirstlane(rowptr[node]);
        const int end = __builtin_amdgcn_readfirstlane(rowptr[node + 1]);
        const int deg = end - beg;
        const int* csp = csrc + beg;
        const float edr = *(const float*)((const char*)ed + ((unsigned)node * 32u + (unsigned)h * 4u));
        float selfe = *(const float*)((const char*)es + ((unsigned)node * 32u + (unsigned)h * 4u)) + edr;
        selfe = selfe > 0.f ? selfe : 0.2f * selfe;

        if (deg <= 64) {
            // ---- Phase A ----
            const int nb = (deg + 7) >> 3;
            const int dm1 = (deg > 0) ? deg - 1 : 0;
            float ex_r[8]; int s_r[8];
            float den = 0.f;
#pragma unroll
            for (int b = 0; b < 8; ++b) { ex_r[b] = 0.f; s_r[b] = 0; }
            if (deg > 0) {
#pragma unroll
                for (int b = 0; b < 8; ++b)
                    if (b < nb) {
                        int k = b * 8 + slot;
                        s_r[b] = csp[k < deg ? k : dm1];
                    }
#pragma unroll
                for (int b = 0; b < 8; ++b)
                    if (b < nb) {
                        float e = *(const float*)((const char*)es +
                                  ((unsigned)s_r[b] * 32u + (unsigned)h * 4u)) + edr;
                        e = e > 0.f ? e : 0.2f * e;
                        float ex = __expf(e - selfe);
                        ex_r[b] = (b * 8 + slot < deg) ? ex : 0.f;
                        den += ex_r[b];
                    }
            }
            den += __shfl_xor(den, 8);
            den += __shfl_xor(den, 16);
            den += __shfl_xor(den, 32);
            const float invden = 1.f / (den + 1.f);
#pragma unroll
            for (int b = 0; b < 8; ++b)
                if (b < nb) salpha[wv][b * 64 + lane] = ex_r[b] * invden;
            if (h == 0) {
#pragma unroll
                for (int b = 0; b < 8; ++b)
                    if (b < nb) ssrcs[wv][b * 8 + slot] = s_r[b];
            }
            if (slot == 0) sself[wv][h] = invden;

            // ---- Phase B: pipelined 8-edge groups; uniform srcs -> saddr loads ----
            floatx2 acc2[4] = {};
            const int ng = nb;
            if (ng > 0) {
                int sA0, sA1, sA2, sA3, sA4, sA5, sA6, sA7;
                int sB0, sB1, sB2, sB3, sB4, sB5, sB6, sB7;
                unsigned rA0, rA1, rA2, rA3, rA4, rA5, rA6, rA7;
                unsigned rB0, rB1, rB2, rB3, rB4, rB5, rB6, rB7;
#define LOAD_BANK(S, R, G) do { \
    const int* sp_ = &ssrcs[wv][(G) * 8]; \
    S##0 = __builtin_amdgcn_readfirstlane(sp_[0]); \
    S##1 = __builtin_amdgcn_readfirstlane(sp_[1]); \
    S##2 = __builtin_amdgcn_readfirstlane(sp_[2]); \
    S##3 = __builtin_amdgcn_readfirstlane(sp_[3]); \
    S##4 = __builtin_amdgcn_readfirstlane(sp_[4]); \
    S##5 = __builtin_amdgcn_readfirstlane(sp_[5]); \
    S##6 = __builtin_amdgcn_readfirstlane(sp_[6]); \
    S##7 = __builtin_amdgcn_readfirstlane(sp_[7]); \
    R##0 = *(const unsigned*)((const char*)actb + ((unsigned)S##0 * 128u + cpo)); \
    R##1 = *(const unsigned*)((const char*)actb + ((unsigned)S##1 * 128u + cpo)); \
    R##2 = *(const unsigned*)((const char*)actb + ((unsigned)S##2 * 128u + cpo)); \
    R##3 = *(const unsigned*)((const char*)actb + ((unsigned)S##3 * 128u + cpo)); \
    R##4 = *(const unsigned*)((const char*)actb + ((unsigned)S##4 * 128u + cpo)); \
    R##5 = *(const unsigned*)((const char*)actb + ((unsigned)S##5 * 128u + cpo)); \
    R##6 = *(const unsigned*)((const char*)actb + ((unsigned)S##6 * 128u + cpo)); \
    R##7 = *(const unsigned*)((const char*)actb + ((unsigned)S##7 * 128u + cpo)); \
} while (0)
#define FMA_BANK(R, G) do { \
    const float* ab_ = &salpha[wv][(G) * 64 + hq * 4]; \
    unsigned rr_[8] = {R##0, R##1, R##2, R##3, R##4, R##5, R##6, R##7}; \
    _Pragma("unroll") \
    for (int j_ = 0; j_ < 8; ++j_) { \
        floatx4 al_ = *(const floatx4*)(ab_ + j_ * 8); \
        floatx2 al01_ = __builtin_shufflevector(al_, al_, 0, 1); \
        floatx2 al23_ = __builtin_shufflevector(al_, al_, 2, 3); \
        floatx2 a2_ = up2(rr_[j_]); \
        pk_fma_lo(acc2[0], a2_, al01_); pk_fma_hi(acc2[1], a2_, al01_); \
        pk_fma_lo(acc2[2], a2_, al23_); pk_fma_hi(acc2[3], a2_, al23_); \
    } \
} while (0)
                LOAD_BANK(sA, rA, 0);
                int g = 0;
                while (true) {
                    if (g + 1 < ng) LOAD_BANK(sB, rB, g + 1);
                    __builtin_amdgcn_sched_barrier(0);
                    FMA_BANK(rA, g);
                    ++g; if (g >= ng) break;
                    if (g + 1 < ng) LOAD_BANK(sA, rA, g + 1);
                    __builtin_amdgcn_sched_barrier(0);
                    FMA_BANK(rB, g);
                    ++g; if (g >= ng) break;
                }
#undef LOAD_BANK
#undef FMA_BANK
            }
            {   // self edge
                unsigned sv = *(const unsigned*)((const char*)actb + ((unsigned)node * 128u + cpo));
                floatx2 a2 = up2(sv);
                floatx4 sa = *(const floatx4*)&sself[wv][hq * 4];
                floatx2 sa01 = __builtin_shufflevector(sa, sa, 0, 1);
                floatx2 sa23 = __builtin_shufflevector(sa, sa, 2, 3);
                pk_fma_lo(acc2[0], a2, sa01); pk_fma_hi(acc2[1], a2, sa01);
                pk_fma_lo(acc2[2], a2, sa23); pk_fma_hi(acc2[3], a2, sa23);
            }
            // stage to LDS agg tile: k = (hq*4+j)*64 + 2cp
#pragma unroll
            for (int j = 0; j < 4; ++j)
                *(unsigned*)&aggt[row][(hq * 4 + j) * 64 + 2 * cp] = pk2(acc2[j].x, acc2[j].y);
        } else {
            // ---- fallback (deg>64, rare): streaming two-pass, full-wave per edge ----
            float acc[NH] = {0.f, 0.f, 0.f, 0.f, 0.f, 0.f, 0.f, 0.f};
            float den = 0.f;
            for (int base = beg; base < end; base += 8) {
                int ei = base + slot;
                if (ei < end) {
                    int s = csrc[ei];
                    float e = es[s * NH + h] + edr;
                    e = e > 0.f ? e : 0.2f * e;
                    den += __expf(e - selfe);
                }
            }
            den += __shfl_xor(den, 8);
            den += __shfl_xor(den, 16);
            den += __shfl_xor(den, 32);
            const float invden = 1.f / (den + 1.f);
            for (int base = beg; base < end; base += 8) {
                int ei = base + slot;
                float al = 0.f; int sl = 0;
                if (ei < end) {
                    sl = csrc[ei];
                    float e = es[sl * NH + h] + edr;
                    e = e > 0.f ? e : 0.2f * e;
                    al = __expf(e - selfe) * invden;
                }
                salpha[wv][lane] = al;
                if (h == 0) ssrcs[wv][slot] = sl;
                int ecnt = end - base; if (ecnt > 8) ecnt = 8;
                for (int j = 0; j < ecnt; ++j) {
                    int s = ssrcs[wv][j];
                    float a = bf2f(actb[(long)s * 64 + lane]);
                    floatx4 al0 = *(const floatx4*)&salpha[wv][j * 8];
                    floatx4 al1 = *(const floatx4*)&salpha[wv][j * 8 + 4];
                    acc[0] += al0[0] * a; acc[1] += al0[1] * a;
                    acc[2] += al0[2] * a; acc[3] += al0[3] * a;
                    acc[4] += al1[0] * a; acc[5] += al1[1] * a;
                    acc[6] += al1[2] * a; acc[7] += al1[3] * a;
                }
            }
            {
                if (slot == 0) sself[wv][h] = invden;
                float a = bf2f(actb[(long)node * 64 + lane]);
                floatx4 s0 = *(const floatx4*)&sself[wv][0];
                floatx4 s1 = *(const floatx4*)&sself[wv][4];
                acc[0] += s0[0] * a; acc[1] += s0[1] * a;
                acc[2] += s0[2] * a; acc[3] += s0[3] * a;
                acc[4] += s1[0] * a; acc[5] += s1[1] * a;
                acc[6] += s1[2] * a; acc[7] += s1[3] * a;
            }
#pragma unroll
            for (int hh = 0; hh < NH; ++hh)
                aggt[row][hh * 64 + lane] = (unsigned short)f2bf_bits(acc[hh]);
        }
    }

    __syncthreads();

    // ================= MFMA projection: [16 x 512] @ [512 x 16*NCT] =================
    const int lr = lane & 15, q = lane >> 4;
    const bool act = wv < NCT;
    floatx4 acc = {};
    if (act) {
#pragma unroll 4
        for (int k0 = 0; k0 < 512; k0 += 32) {
            bf16x8 a = __builtin_bit_cast(bf16x8,
                *(const short8*)&aggt[lr][k0 + q * 8]);
            bf16x8 b = __builtin_bit_cast(bf16x8,
                *(const short8*)((const short*)wgT + (long)(wv * 16 + lr) * 512 + k0 + q * 8));
            acc = __builtin_amdgcn_mfma_f32_16x16x32_bf16(a, b, acc, 0, 0, 0);
        }
    }

    if (EPI == 2) {
        if (act) {
#pragma unroll
            for (int r = 0; r < 4; ++r) {
                int node = blockIdx.x * 16 + q * 4 + r;
                int col = wv * 16 + lr;
                float v = acc[r] * 0.125f + bias[col];
                ((bf16*)outp)[(long)node * 64 + col] = __float2bfloat16(fmaxf(v, 0.f));
            }
        }
    } else {
        // log_softmax across 32 cols held by waves 0 (cols 0-15) and 1 (cols 16-31)
        float v[4], m[4];
#pragma unroll
        for (int r = 0; r < 4; ++r) {
            v[r] = acc[r] * 0.125f + (act ? bias[wv * 16 + lr] : 0.f);
            m[r] = v[r];
        }
#pragma unroll
        for (int off = 1; off < 16; off <<= 1)
#pragma unroll
            for (int r = 0; r < 4; ++r) m[r] = fmaxf(m[r], __shfl_xor(m[r], off));
        if (act && lr == 0) {
#pragma unroll
            for (int r = 0; r < 4; ++r) redbuf[0][wv][q * 4 + r] = m[r];
        }
        __syncthreads();
        float s[4];
#pragma unroll
        for (int r = 0; r < 4; ++r) {
            float mm_ = fmaxf(redbuf[0][0][q * 4 + r], redbuf[0][1][q * 4 + r]);
            m[r] = mm_;
            s[r] = act ? __expf(v[r] - mm_) : 0.f;
        }
#pragma unroll
        for (int off = 1; off < 16; off <<= 1)
#pragma unroll
            for (int r = 0; r < 4; ++r) s[r] += __shfl_xor(s[r], off);
        if (act && lr == 0) {
#pragma unroll
            for (int r = 0; r < 4; ++r) redbuf[1][wv][q * 4 + r] = s[r];
        }
        __syncthreads();
        if (act) {
#pragma unroll
            for (int r = 0; r < 4; ++r) {
                int row = q * 4 + r;
                int node = blockIdx.x * 16 + row;
                float ls = m[r] + logf(redbuf[1][0][row] + redbuf[1][1][row]);
                ((float*)outp)[(long)node * 32 + wv * 16 + lr] = v[r] - ls;
            }
        }
    }
}

// ---------------- launch ----------------
extern "C" void kernel_launch(void* const* d_in, const int* in_sizes, int n_in,
                              void* d_out, int out_size, void* d_ws, size_t ws_size,
                              hipStream_t stream) {
    const float* x        = (const float*)d_in[0];
    const int*   eidx     = (const int*)d_in[1];
    const float* gcn1_w   = (const float*)d_in[2];
    const float* gcn1_b   = (const float*)d_in[3];
    const float* bn1_g    = (const float*)d_in[4];
    const float* bn1_b    = (const float*)d_in[5];
    const float* bn1_m    = (const float*)d_in[6];
    const float* bn1_v    = (const float*)d_in[7];
    const float* gat1_w   = (const float*)d_in[8];
    const float* gat1_as  = (const float*)d_in[9];
    const float* gat1_ad  = (const float*)d_in[10];
    const float* gat1_b   = (const float*)d_in[11];
    const float* gcn2_w   = (const float*)d_in[12];
    const float* gcn2_b   = (const float*)d_in[13];
    const float* bn2_g    = (const float*)d_in[14];
    const float* bn2_b    = (const float*)d_in[15];
    const float* bn2_m    = (const float*)d_in[16];
    const float* bn2_v    = (const float*)d_in[17];
    const float* gat2_w   = (const float*)d_in[18];
    const float* gat2_as  = (const float*)d_in[19];
    const float* gat2_ad  = (const float*)d_in[20];
    const float* gat2_b   = (const float*)d_in[21];
    float* out = (float*)d_out;

    const int* esrc = eidx;
    const int* edst = eidx + NE;

    // workspace (~78 MB, < proven-safe 110.6 MB)
    float* ws = (float*)d_ws;
    int*      ghist  = (int*)ws;                        // GH
    int*      gpre   = ghist + GH;                      // GH
    int*      gbsum  = gpre + GH;                       // 512 (unscanned block sums)
    unsigned* ebuf   = (unsigned*)(gbsum + 512);        // NE
    int*      rowptr = (int*)(ebuf + NE);               // 50048
    int*      csrc   = rowptr + 50048;                  // NE
    float*    dinv   = (float*)(csrc + NE);             // 50048
    float*    es     = dinv + 50048;                    // 400000
    float*    ed     = es + 400000;                     // 400000
    float*    was1   = ed + 400000;                     // 512
    float*    wad1   = was1 + 512;                      // 512
    float*    was2   = wad1 + 512;                      // 512
    float*    wad2   = was2 + 512;                      // 512
    bf16*     wT1    = (bf16*)(wad2 + 512);             // 64*128
    bf16*     wT2    = wT1 + 64 * 128;                  // 64*64
    bf16*     wgT1   = wT2 + 64 * 64;                   // 64*512
    bf16*     wgT2   = wgT1 + 64 * 512;                 // 64*512
    bf16*     actb   = wgT2 + 64 * 512;                 // N*64 bf16
    bf16*     mmbf   = actb + (size_t)NN * 64;          // N*64 bf16
    bf16*     gact   = mmbf + (size_t)NN * 64;          // N*64 bf16 (reuses old agg region)

    auto cdiv = [](long a, long b) { return (int)((a + b - 1) / b); };
    const int GB = cdiv(NN, 64);
    const int NB = cdiv(NN, 4);
    const int FB = NN / 16;   // 3125 exact

    // ---- CSR build ----
    bin_count_prep_kernel<<<EBLK + PREPB, 256, 0, stream>>>(edst, ghist,
        gcn1_w, gcn2_w, gat1_w, gat2_w, gat1_as, gat1_ad, gat2_as, gat2_ad,
        wT1, wT2, wgT1, wgT2, was1, wad1, was2, wad2);
    scang1_kernel<<<GH / 256, 256, 0, stream>>>(ghist, gpre, gbsum, GH);
    bin_scatter_kernel<<<EBLK, 256, 0, stream>>>(esrc, edst, gpre, gbsum, ebuf);
    bucket_finalize_kernel<<<NBUK, 256, 0, stream>>>(ebuf, gpre, gbsum, rowptr, dinv, csrc);

    // ---- GCN1 ----
    mm2_kernel<IND, 3, true><<<GB, 256, 0, stream>>>(x, wT1, mmbf, nullptr, dinv, NN, 64);
    gcn_fused_kernel<<<NB, 256, 0, stream>>>(rowptr, csrc, dinv, mmbf,
        gcn1_b, bn1_g, bn1_b, bn1_m, bn1_v, actb);

    // ---- GAT1 (C=64), fully fused ----
    scores_kernel<<<NB, 256, 0, stream>>>(actb, was1, wad1, es, ed, NN);
    gat_fused_kernel<4, 2><<<FB, 256, 0, stream>>>(rowptr, csrc, es, ed, actb, wgT1, gat1_b, gact);

    // ---- GCN2 ----
    mm2_kernel<64, 3, false><<<GB, 256, 0, stream>>>(gact, wT2, mmbf, nullptr, dinv, NN, 64);
    gcn_fused_kernel<<<NB, 256, 0, stream>>>(rowptr, csrc, dinv, mmbf,
        gcn2_b, bn2_g, bn2_b, bn2_m, bn2_v, actb);

    // ---- GAT2 (C=32) + fused log_softmax -> out ----
    scores_kernel<<<NB, 256, 0, stream>>>(actb, was2, wad2, es, ed, NN);
    gat_fused_kernel<2, 4><<<FB, 256, 0, stream>>>(rowptr, csrc, es, ed, actb, wgT2, gat2_b, out);
}